// Round 10
// baseline (1727.003 us; speedup 1.0000x reference)
//
#include <hip/hip_runtime.h>
#include <stdint.h>

typedef _Float16 f16;
typedef __attribute__((ext_vector_type(8))) _Float16 f16x8;
typedef __attribute__((ext_vector_type(4))) _Float16 f16x4;
typedef __attribute__((ext_vector_type(4))) float f32x4;

// Tiled weight layout in ws (f16 elems), K-tile = 32, tiles n-major [n][32]:
// W1: 4 tiles of [512][32]; W2: 16 tiles of [512][32]; W3: 16 tiles of [256][32]
// (n>=251 zeroed). Wave w's slice of each tile is contiguous (NT*1024B).
#define WS_W1 0
#define WS_W2 65536
#define WS_W3 327680
#define PROBE_OFF 917504        // dead gap between weights end and LG_OFF
#define LG_OFF (1 << 20)        // byte offset of lgT region in d_ws
#define CHUNK_ROWS 32768

// ------------------------- clock probe (dependent FMA) -----------------------
// 65536-deep dependent FMA chain ~= 262144 cycles. dur_us = 262144 / f(MHz).
// ~110us @2.4GHz, ~520us @500MHz, ~870us @300MHz.
__global__ __launch_bounds__(64) void probe_k(float* __restrict__ o) {
  float x = 1.1f + (float)threadIdx.x * 1e-6f;
  #pragma unroll 1
  for (int i = 0; i < 8192; ++i) {
    #pragma unroll
    for (int j = 0; j < 8; ++j) x = __builtin_fmaf(x, 1.0000001f, 1e-9f);
  }
  o[threadIdx.x] = x;
}

__global__ __launch_bounds__(256) void convert_weights_k(
    const float* __restrict__ W1, const float* __restrict__ W2,
    const float* __restrict__ W3, f16* __restrict__ ws)
{
  int idx = blockIdx.x * 256 + threadIdx.x;
  if (idx < 65536) {
    int kt = idx >> 14, r = idx & 16383, n = r >> 5, kk = r & 31;
    ws[WS_W1 + idx] = (f16)W1[(kt * 32 + kk) * 512 + n];
  } else if (idx < 327680) {
    int i = idx - 65536;
    int kt = i >> 14, r = i & 16383, n = r >> 5, kk = r & 31;
    ws[WS_W2 + i] = (f16)W2[(kt * 32 + kk) * 512 + n];
  } else if (idx < 458752) {
    int i = idx - 327680;
    int kt = i >> 13, r = i & 8191, n = r >> 5, kk = r & 31;
    ws[WS_W3 + i] = (n < 251) ? (f16)W3[(kt * 32 + kk) * 251 + n] : (f16)0.0f;
  }
}

__device__ __forceinline__ f16x8 lds_ld8(const char* base, int m, int strideB, int kb) {
  return *(const f16x8*)(base + m * strideB + (kb ^ ((m & 7) << 4)));
}

__device__ __forceinline__ f16x8 load_x_frag(
    const float* __restrict__ obs, const float* __restrict__ act, long row, int e)
{
  const float* p = (e < 96) ? (obs + row * 96 + e) : (act + row * 32 + (e - 96));
  float4 lo = ((const float4*)p)[0];
  float4 hi = ((const float4*)p)[1];
  f16x8 v;
  v[0] = (f16)lo.x; v[1] = (f16)lo.y; v[2] = (f16)lo.z; v[3] = (f16)lo.w;
  v[4] = (f16)hi.x; v[5] = (f16)hi.y; v[6] = (f16)hi.z; v[7] = (f16)hi.w;
  return v;
}

// --------------------------- GEMM building blocks ---------------------------
template<int KT, int NT>
__device__ __forceinline__ void mlp_stage_reg(
    const char* __restrict__ wlane, int tileB,
    const char* __restrict__ src, int srcStride,
    f32x4 acc[4][NT], int l15, int lh)
{
  #pragma unroll
  for (int kt = 0; kt < KT; ++kt) {
    f16x8 a[NT];
    const char* g = wlane + (size_t)kt * tileB;
    #pragma unroll
    for (int nt = 0; nt < NT; ++nt) a[nt] = *(const f16x8*)(g + nt * 1024);
    __builtin_amdgcn_s_setprio(1);
    #pragma unroll
    for (int mh = 0; mh < 4; ++mh) {
      f16x8 b = lds_ld8(src, mh * 16 + l15, srcStride, kt * 64 + lh * 16);
      #pragma unroll
      for (int nt = 0; nt < NT; ++nt)
        acc[mh][nt] = __builtin_amdgcn_mfma_f32_16x16x32_f16(a[nt], b, acc[mh][nt], 0, 0, 0);
    }
    __builtin_amdgcn_s_setprio(0);
  }
}

__device__ __forceinline__ void mlp_stage1(
    const float* __restrict__ obs, const float* __restrict__ act, long rowBase,
    const char* __restrict__ wlane, f32x4 acc[4][4], int l15, int lh)
{
  #pragma unroll
  for (int kt = 0; kt < 4; ++kt) {
    f16x8 a[4];
    const char* g = wlane + (size_t)kt * 32768;
    #pragma unroll
    for (int nt = 0; nt < 4; ++nt) a[nt] = *(const f16x8*)(g + nt * 1024);
    int e = kt * 32 + lh * 8;
    #pragma unroll
    for (int mh = 0; mh < 4; ++mh) {
      f16x8 b = load_x_frag(obs, act, rowBase + mh * 16 + l15, e);
      #pragma unroll
      for (int nt = 0; nt < 4; ++nt)
        acc[mh][nt] = __builtin_amdgcn_mfma_f32_16x16x32_f16(a[nt], b, acc[mh][nt], 0, 0, 0);
    }
  }
}

template<int NT>
__device__ __forceinline__ void store_act(
    f32x4 acc[4][NT], char* hbuf, const float* __restrict__ bias,
    int w, int l15, int lh)
{
  #pragma unroll
  for (int nt = 0; nt < NT; ++nt) {
    int ncol = w * (NT * 16) + nt * 16 + lh * 4;
    f32x4 bv = *(const f32x4*)(bias + ncol);
    #pragma unroll
    for (int mh = 0; mh < 4; ++mh) {
      int m = mh * 16 + l15;
      f16x4 hv;
      #pragma unroll
      for (int r = 0; r < 4; ++r) {
        float v = acc[mh][nt][r] + bv[r];
        hv[r] = (f16)(v > 0.f ? v : 0.01f * v);
      }
      *(f16x4*)(hbuf + m * 1024 + ((ncol * 2) ^ ((m & 7) << 4))) = hv;
    }
  }
}

// ------------------------ split kernel 1: MLP -> lgT -------------------------
__global__ __launch_bounds__(512, 4) void gemm3_k(
    const float* __restrict__ obs, const float* __restrict__ act,
    const float* __restrict__ bias1, const float* __restrict__ bias2,
    const float* __restrict__ bias3, const f16* __restrict__ ws,
    float* __restrict__ lgT, long rowBase0)
{
  extern __shared__ char smem[];
  char* hbuf = smem;                      // 64KB
  const int tid = threadIdx.x;
  const int lane = tid & 63;
  const int w = tid >> 6;
  const int l15 = lane & 15;
  const int lh = lane >> 4;
  const int localRowBase = blockIdx.x * 64;
  const long rowBase = rowBase0 + localRowBase;

  {
    f32x4 acc[4][4];
    #pragma unroll
    for (int mh = 0; mh < 4; ++mh)
      #pragma unroll
      for (int nt = 0; nt < 4; ++nt) acc[mh][nt] = f32x4{0.f, 0.f, 0.f, 0.f};
    const char* wl = (const char*)(ws + WS_W1) + (w * 64 + l15) * 64 + lh * 16;
    mlp_stage1(obs, act, rowBase, wl, acc, l15, lh);
    store_act<4>(acc, hbuf, bias1, w, l15, lh);
  }
  __syncthreads();
  {
    f32x4 acc[4][4];
    #pragma unroll
    for (int mh = 0; mh < 4; ++mh)
      #pragma unroll
      for (int nt = 0; nt < 4; ++nt) acc[mh][nt] = f32x4{0.f, 0.f, 0.f, 0.f};
    const char* wl = (const char*)(ws + WS_W2) + (w * 64 + l15) * 64 + lh * 16;
    mlp_stage_reg<16, 4>(wl, 32768, hbuf, 1024, acc, l15, lh);
    __syncthreads();
    store_act<4>(acc, hbuf, bias2, w, l15, lh);
  }
  __syncthreads();
  {
    f32x4 acc[4][2];
    #pragma unroll
    for (int mh = 0; mh < 4; ++mh)
      #pragma unroll
      for (int nt = 0; nt < 2; ++nt) acc[mh][nt] = f32x4{0.f, 0.f, 0.f, 0.f};
    const char* wl = (const char*)(ws + WS_W3) + (w * 32 + l15) * 64 + lh * 16;
    mlp_stage_reg<16, 2>(wl, 16384, hbuf, 1024, acc, l15, lh);
    #pragma unroll
    for (int nt = 0; nt < 2; ++nt) {
      int abase = w * 32 + nt * 16 + lh * 4;
      float bv[4];
      #pragma unroll
      for (int r = 0; r < 4; ++r) {
        int a = abase + r;
        bv[r] = (a < 251) ? bias3[a] : 0.f;
      }
      #pragma unroll
      for (int mh = 0; mh < 4; ++mh) {
        int m = mh * 16 + l15;
        #pragma unroll
        for (int r = 0; r < 4; ++r) {
          int a = abase + r;
          if (a < 251)
            lgT[(size_t)a * CHUNK_ROWS + localRowBase + m] = acc[mh][nt][r] + bv[r];
        }
      }
    }
  }
}

// ------------------- split kernel 2: softmax + projection -------------------
template<int VAR>
__global__ __launch_bounds__(512, 2) void epi_c51_k(
    const float* __restrict__ lgT,
    const float* __restrict__ rewards, const float* __restrict__ bootstrap,
    const float* __restrict__ discount, const float* __restrict__ q_support,
    float* __restrict__ out, long rowBase0)
{
  __shared__ float sh[16384];

  const int tid = threadIdx.x;
  const int lane = tid & 63;
  const int w = tid >> 6;
  const int localRowBase = blockIdx.x * 64;
  const long rowBase = rowBase0 + localRowBase;
  const int a0 = w * 32;

  float e[32];
  #pragma unroll
  for (int i = 0; i < 32; ++i) {
    int a = a0 + i;
    e[i] = (a < 251) ? lgT[(size_t)a * CHUNK_ROWS + localRowBase + lane] : -3.0e38f;
  }
  float m0 = e[0], m1 = e[1], m2 = e[2], m3 = e[3];
  #pragma unroll
  for (int i = 4; i < 32; i += 4) {
    m0 = fmaxf(m0, e[i]);     m1 = fmaxf(m1, e[i + 1]);
    m2 = fmaxf(m2, e[i + 2]); m3 = fmaxf(m3, e[i + 3]);
  }
  sh[w * 64 + lane] = fmaxf(fmaxf(m0, m1), fmaxf(m2, m3));
  float rw = rewards[rowBase + lane];
  float bd = __fmul_rn(bootstrap[rowBase + lane], discount[rowBase + lane]);
  __syncthreads();

  float mx = sh[lane];
  #pragma unroll
  for (int ww = 1; ww < 8; ++ww) mx = fmaxf(mx, sh[ww * 64 + lane]);
  float s0 = 0.f, s1 = 0.f, s2 = 0.f, s3 = 0.f;
  #pragma unroll
  for (int i = 0; i < 32; i += 4) {
    e[i]     = __expf(e[i]     - mx); s0 += e[i];
    e[i + 1] = __expf(e[i + 1] - mx); s1 += e[i + 1];
    e[i + 2] = __expf(e[i + 2] - mx); s2 += e[i + 2];
    e[i + 3] = __expf(e[i + 3] - mx); s3 += e[i + 3];
  }
  sh[512 + w * 64 + lane] = (s0 + s1) + (s2 + s3);
  __syncthreads();

  float tot = sh[512 + lane];
  #pragma unroll
  for (int ww = 1; ww < 8; ++ww) tot += sh[512 + ww * 64 + lane];
  float inv = 1.f / tot;
  __syncthreads();

  #pragma unroll
  for (int z = 0; z < 8; ++z)
    *(f32x4*)((char*)sh + (z * 512 + tid) * 16) = f32x4{0.f, 0.f, 0.f, 0.f};
  __syncthreads();

  #pragma unroll
  for (int i = 0; i < 32; ++i) {
    int a = a0 + i;
    if (a < 251) {
      float p = e[i] * inv;
      float zc = q_support[a];
      float tz = __fadd_rn(rw, __fmul_rn(bd, zc));
      tz = fminf(fmaxf(tz, -100.f), 100.f);
      float b = __fdiv_rn(__fadd_rn(tz, 100.f), 0.8f);
      float lf = floorf(b), uf = ceilf(b);
      int li = (int)lf, ui = (int)uf;
      bool eq = (li == ui);
      int li2 = li - ((eq && (ui > 0)) ? 1 : 0);
      int ui2 = ui + ((eq && (li < 250)) ? 1 : 0);
      atomicAdd(&sh[li2 * 64 + (lane ^ (li2 & 31))], p * ((float)ui2 - b));
      atomicAdd(&sh[ui2 * 64 + (lane ^ (ui2 & 31))], p * (b - (float)li2));
    }
  }
  __syncthreads();

  #pragma unroll 1
  for (int rr = 0; rr < 8; ++rr) {
    int row = w * 8 + rr;
    #pragma unroll
    for (int j = 0; j < 4; ++j) {
      int c = lane + j * 64;
      if (c < 251)
        out[(rowBase + row) * 251 + c] = sh[c * 64 + (row ^ (c & 31))];
    }
  }
}

// ---------------- ABLATION A: lgT loads + softmax (x8, rotated slices) ------
__global__ __launch_bounds__(512, 2) void epi_ablA_k(
    const float* __restrict__ lgT, float* __restrict__ out)
{
  __shared__ float sh[16384];   // sized to match real epi residency
  const int tid = threadIdx.x, lane = tid & 63, w = tid >> 6;
  const int a0 = w * 32;
  float acc = 0.f;
  #pragma unroll 1
  for (int rep = 0; rep < 8; ++rep) {
    int lrb = ((blockIdx.x + rep * 67) & 511) * 64;   // rotate slices: no L1-hot reps
    float e[32];
    #pragma unroll
    for (int i = 0; i < 32; ++i) {
      int a = a0 + i;
      e[i] = (a < 251) ? lgT[(size_t)a * CHUNK_ROWS + lrb + lane] : -3.0e38f;
    }
    float m0 = e[0], m1 = e[1], m2 = e[2], m3 = e[3];
    #pragma unroll
    for (int i = 4; i < 32; i += 4) {
      m0 = fmaxf(m0, e[i]);     m1 = fmaxf(m1, e[i + 1]);
      m2 = fmaxf(m2, e[i + 2]); m3 = fmaxf(m3, e[i + 3]);
    }
    sh[w * 64 + lane] = fmaxf(fmaxf(m0, m1), fmaxf(m2, m3));
    __syncthreads();
    float mx = sh[lane];
    #pragma unroll
    for (int ww = 1; ww < 8; ++ww) mx = fmaxf(mx, sh[ww * 64 + lane]);
    float s0 = 0.f, s1 = 0.f, s2 = 0.f, s3 = 0.f;
    #pragma unroll
    for (int i = 0; i < 32; i += 4) {
      e[i]     = __expf(e[i]     - mx); s0 += e[i];
      e[i + 1] = __expf(e[i + 1] - mx); s1 += e[i + 1];
      e[i + 2] = __expf(e[i + 2] - mx); s2 += e[i + 2];
      e[i + 3] = __expf(e[i + 3] - mx); s3 += e[i + 3];
    }
    sh[512 + w * 64 + lane] = (s0 + s1) + (s2 + s3);
    __syncthreads();
    float tot = sh[512 + lane];
    #pragma unroll
    for (int ww = 1; ww < 8; ++ww) tot += sh[512 + ww * 64 + lane];
    acc += 1.f / tot;
    __syncthreads();
  }
  // chunk-0 rows; overwritten by the real pipeline afterwards
  out[((size_t)blockIdx.x * 64 + lane) * 251 + w] = acc;
}

// ------- ABLATION B: zero + projection fp-chain + atomics + stores (x8) -----
__global__ __launch_bounds__(512, 2) void epi_ablB_k(
    const float* __restrict__ rewards, const float* __restrict__ bootstrap,
    const float* __restrict__ discount, const float* __restrict__ q_support,
    float* __restrict__ out)
{
  __shared__ float sh[16384];
  const int tid = threadIdx.x, lane = tid & 63, w = tid >> 6;
  const int a0 = w * 32;
  const int localRowBase = blockIdx.x * 64;
  float e[32];
  #pragma unroll
  for (int i = 0; i < 32; ++i)
    e[i] = 1.0f + (float)((lane * 37 + i * 11) & 63) * 0.01f;
  float inv = 0.0041f;
  float rw = rewards[localRowBase + lane];
  float bd = __fmul_rn(bootstrap[localRowBase + lane], discount[localRowBase + lane]);
  #pragma unroll 1
  for (int rep = 0; rep < 8; ++rep) {
    asm volatile("" : "+v"(bd), "+v"(inv));   // defeat hoist/CSE across reps
    #pragma unroll
    for (int z = 0; z < 8; ++z)
      *(f32x4*)((char*)sh + (z * 512 + tid) * 16) = f32x4{0.f, 0.f, 0.f, 0.f};
    __syncthreads();
    #pragma unroll
    for (int i = 0; i < 32; ++i) {
      int a = a0 + i;
      if (a < 251) {
        float p = e[i] * inv;
        float zc = q_support[a];
        float tz = __fadd_rn(rw, __fmul_rn(bd, zc));
        tz = fminf(fmaxf(tz, -100.f), 100.f);
        float b = __fdiv_rn(__fadd_rn(tz, 100.f), 0.8f);
        float lf = floorf(b), uf = ceilf(b);
        int li = (int)lf, ui = (int)uf;
        bool eq = (li == ui);
        int li2 = li - ((eq && (ui > 0)) ? 1 : 0);
        int ui2 = ui + ((eq && (li < 250)) ? 1 : 0);
        atomicAdd(&sh[li2 * 64 + (lane ^ (li2 & 31))], p * ((float)ui2 - b));
        atomicAdd(&sh[ui2 * 64 + (lane ^ (ui2 & 31))], p * (b - (float)li2));
      }
    }
    __syncthreads();
    #pragma unroll 1
    for (int rr = 0; rr < 8; ++rr) {
      int row = w * 8 + rr;
      #pragma unroll
      for (int j = 0; j < 4; ++j) {
        int c = lane + j * 64;
        if (c < 251)
          out[(size_t)(localRowBase + row) * 251 + c] = sh[c * 64 + (row ^ (c & 31))];
      }
    }
    __syncthreads();
  }
}

// ----------------- fallback: round-7 fused kernel (ws too small) ------------
__global__ __launch_bounds__(512, 4) void fused_c51_k(
    const float* __restrict__ obs, const float* __restrict__ act,
    const float* __restrict__ rewards, const float* __restrict__ bootstrap,
    const float* __restrict__ discount, const float* __restrict__ q_support,
    const float* __restrict__ bias1, const float* __restrict__ bias2,
    const float* __restrict__ bias3, const f16* __restrict__ ws,
    float* __restrict__ out)
{
  extern __shared__ char smem[];
  char* hbuf = smem;
  float* pmax = (float*)(smem + 65536);
  float* psum = (float*)(smem + 65536 + 2048);
  const int tid = threadIdx.x;
  const int lane = tid & 63;
  const int w = tid >> 6;
  const int l15 = lane & 15;
  const int lh = lane >> 4;
  const long rowBase = (long)blockIdx.x * 64;

  {
    f32x4 acc[4][4];
    #pragma unroll
    for (int mh = 0; mh < 4; ++mh)
      #pragma unroll
      for (int nt = 0; nt < 4; ++nt) acc[mh][nt] = f32x4{0.f, 0.f, 0.f, 0.f};
    const char* wl = (const char*)(ws + WS_W1) + (w * 64 + l15) * 64 + lh * 16;
    mlp_stage1(obs, act, rowBase, wl, acc, l15, lh);
    store_act<4>(acc, hbuf, bias1, w, l15, lh);
  }
  __syncthreads();
  {
    f32x4 acc[4][4];
    #pragma unroll
    for (int mh = 0; mh < 4; ++mh)
      #pragma unroll
      for (int nt = 0; nt < 4; ++nt) acc[mh][nt] = f32x4{0.f, 0.f, 0.f, 0.f};
    const char* wl = (const char*)(ws + WS_W2) + (w * 64 + l15) * 64 + lh * 16;
    mlp_stage_reg<16, 4>(wl, 32768, hbuf, 1024, acc, l15, lh);
    __syncthreads();
    store_act<4>(acc, hbuf, bias2, w, l15, lh);
  }
  __syncthreads();
  {
    f32x4 acc[4][2];
    #pragma unroll
    for (int mh = 0; mh < 4; ++mh)
      #pragma unroll
      for (int nt = 0; nt < 2; ++nt) acc[mh][nt] = f32x4{0.f, 0.f, 0.f, 0.f};
    const char* wl = (const char*)(ws + WS_W3) + (w * 32 + l15) * 64 + lh * 16;
    mlp_stage_reg<16, 2>(wl, 16384, hbuf, 1024, acc, l15, lh);
    __syncthreads();
    #pragma unroll
    for (int nt = 0; nt < 2; ++nt) {
      int abase = w * 32 + nt * 16 + lh * 4;
      float bv[4];
      #pragma unroll
      for (int r = 0; r < 4; ++r) {
        int a = abase + r;
        bv[r] = (a < 251) ? bias3[a] : 0.f;
      }
      #pragma unroll
      for (int mh = 0; mh < 4; ++mh) {
        int m = mh * 16 + l15;
        #pragma unroll
        for (int r = 0; r < 4; ++r) {
          int a = abase + r;
          ((float*)hbuf)[a * 64 + m] = (a < 251) ? (acc[mh][nt][r] + bv[r]) : -3.0e38f;
        }
      }
    }
  }
  __syncthreads();
  {
    const float* lgT = (const float*)hbuf;
    float* prT = (float*)hbuf;
    const int a0 = w * 32;
    float e[32];
    #pragma unroll
    for (int i = 0; i < 32; ++i) e[i] = lgT[(a0 + i) * 64 + lane];
    float m0 = e[0], m1 = e[1], m2 = e[2], m3 = e[3];
    #pragma unroll
    for (int i = 4; i < 32; i += 4) {
      m0 = fmaxf(m0, e[i]);     m1 = fmaxf(m1, e[i + 1]);
      m2 = fmaxf(m2, e[i + 2]); m3 = fmaxf(m3, e[i + 3]);
    }
    pmax[w * 64 + lane] = fmaxf(fmaxf(m0, m1), fmaxf(m2, m3));
    float rw = rewards[rowBase + lane];
    float bd = __fmul_rn(bootstrap[rowBase + lane], discount[rowBase + lane]);
    __syncthreads();
    #pragma unroll
    for (int z = 0; z < 8; ++z)
      *(f32x4*)(hbuf + (z * 512 + tid) * 16) = f32x4{0.f, 0.f, 0.f, 0.f};
    float mx = pmax[lane];
    #pragma unroll
    for (int ww = 1; ww < 8; ++ww) mx = fmaxf(mx, pmax[ww * 64 + lane]);
    float s0 = 0.f, s1 = 0.f, s2 = 0.f, s3 = 0.f;
    #pragma unroll
    for (int i = 0; i < 32; i += 4) {
      e[i]     = __expf(e[i]     - mx); s0 += e[i];
      e[i + 1] = __expf(e[i + 1] - mx); s1 += e[i + 1];
      e[i + 2] = __expf(e[i + 2] - mx); s2 += e[i + 2];
      e[i + 3] = __expf(e[i + 3] - mx); s3 += e[i + 3];
    }
    psum[w * 64 + lane] = (s0 + s1) + (s2 + s3);
    __syncthreads();
    float tot = psum[lane];
    #pragma unroll
    for (int ww = 1; ww < 8; ++ww) tot += psum[ww * 64 + lane];
    float inv = 1.f / tot;
    #pragma unroll
    for (int i = 0; i < 32; ++i) {
      int a = a0 + i;
      if (a < 251) {
        float p = e[i] * inv;
        float zc = q_support[a];
        float tz = __fadd_rn(rw, __fmul_rn(bd, zc));
        tz = fminf(fmaxf(tz, -100.f), 100.f);
        float b = __fdiv_rn(__fadd_rn(tz, 100.f), 0.8f);
        float lf = floorf(b), uf = ceilf(b);
        int li = (int)lf, ui = (int)uf;
        bool eq = (li == ui);
        int li2 = li - ((eq && (ui > 0)) ? 1 : 0);
        int ui2 = ui + ((eq && (li < 250)) ? 1 : 0);
        atomicAdd(&prT[li2 * 64 + (lane ^ (li2 & 31))], p * ((float)ui2 - b));
        atomicAdd(&prT[ui2 * 64 + (lane ^ (ui2 & 31))], p * (b - (float)li2));
      }
    }
    __syncthreads();
    for (unsigned i = tid; i < 64u * 251u; i += 512u) {
      unsigned row = i / 251u;
      unsigned c = i - row * 251u;
      out[rowBase * 251 + i] = prT[c * 64 + (row ^ (c & 31))];
    }
  }
}

extern "C" void kernel_launch(void* const* d_in, const int* in_sizes, int n_in,
                              void* d_out, int out_size, void* d_ws, size_t ws_size,
                              hipStream_t stream) {
  (void)n_in; (void)out_size;
  const float* obs       = (const float*)d_in[0];
  const float* actions   = (const float*)d_in[1];
  const float* rewards   = (const float*)d_in[2];
  const float* bootstrap = (const float*)d_in[3];
  const float* discount  = (const float*)d_in[4];
  const float* q_support = (const float*)d_in[5];
  const float* W1 = (const float*)d_in[6];
  const float* b1 = (const float*)d_in[7];
  const float* W2 = (const float*)d_in[8];
  const float* b2 = (const float*)d_in[9];
  const float* W3 = (const float*)d_in[10];
  const float* b3 = (const float*)d_in[11];
  float* out = (float*)d_out;
  f16* ws = (f16*)d_ws;
  const int B = in_sizes[2];

  const size_t need = (size_t)LG_OFF + (size_t)251 * CHUNK_ROWS * 4;
  const bool split = (ws_size >= need) && (B % CHUNK_ROWS == 0);

  if (split) {
    float* lgT = (float*)((char*)d_ws + LG_OFF);
    float* probe_out = (float*)((char*)d_ws + PROBE_OFF);

    // --- measurement probes & ablations (outputs overwritten below) ---
    hipLaunchKernelGGL(probe_k, dim3(1), dim3(64), 0, stream, probe_out);        // P1
    hipLaunchKernelGGL(epi_ablA_k, dim3(CHUNK_ROWS / 64), dim3(512), 0, stream,
                       lgT, out);
    hipLaunchKernelGGL(epi_ablB_k, dim3(CHUNK_ROWS / 64), dim3(512), 0, stream,
                       rewards, bootstrap, discount, q_support, out);

    // --- real pipeline (R9 control) ---
    hipLaunchKernelGGL(convert_weights_k, dim3(1792), dim3(256), 0, stream,
                       W1, W2, W3, ws);
    const int GEMM_LDS = 65536;
    hipFuncSetAttribute(reinterpret_cast<const void*>(gemm3_k),
                        hipFuncAttributeMaxDynamicSharedMemorySize, GEMM_LDS);
    for (int c = 0; c < B / CHUNK_ROWS; ++c) {
      long rb = (long)c * CHUNK_ROWS;
      hipLaunchKernelGGL(gemm3_k, dim3(CHUNK_ROWS / 64), dim3(512), GEMM_LDS, stream,
                         obs, actions, b1, b2, b3, ws, lgT, rb);
      hipLaunchKernelGGL((epi_c51_k<0>), dim3(CHUNK_ROWS / 64), dim3(512), 0, stream,
                         lgT, rewards, bootstrap, discount, q_support, out, rb);
    }

    hipLaunchKernelGGL(probe_k, dim3(1), dim3(64), 0, stream,
                       probe_out + 64);                                          // P2
  } else {
    hipLaunchKernelGGL(convert_weights_k, dim3(1792), dim3(256), 0, stream,
                       W1, W2, W3, ws);
    const int LDS_BYTES = 69632;
    hipFuncSetAttribute(reinterpret_cast<const void*>(fused_c51_k),
                        hipFuncAttributeMaxDynamicSharedMemorySize, LDS_BYTES);
    hipLaunchKernelGGL(fused_c51_k, dim3(B / 64), dim3(512), LDS_BYTES, stream,
                       obs, actions, rewards, bootstrap, discount, q_support,
                       b1, b2, b3, ws, out);
  }
}

// Round 11
// 1468.172 us; speedup vs baseline: 1.1763x; 1.1763x over previous
//
#include <hip/hip_runtime.h>
#include <stdint.h>

typedef _Float16 f16;
typedef __attribute__((ext_vector_type(8))) _Float16 f16x8;
typedef __attribute__((ext_vector_type(4))) _Float16 f16x4;
typedef __attribute__((ext_vector_type(4))) float f32x4;

#define WS_W1 0
#define WS_W2 65536
#define WS_W3 327680
#define PROBE_OFF 917504
#define LG_OFF (1 << 20)
#define CHUNK_ROWS 32768
#define LG_ELEMS ((size_t)251 * CHUNK_ROWS)

// ---------------- all-CU clock probe: 2048 blocks, dep-FMA chain -------------
// 8 waves/SIMD x 8192 FMA x 2cyc = 131k cyc/SIMD. ~55us @2.4GHz, ~330 @400MHz.
__global__ __launch_bounds__(256, 8) void loadprobe_k(float* __restrict__ o) {
  float x = 1.1f + (float)threadIdx.x * 1e-6f;
  #pragma unroll 1
  for (int i = 0; i < 1024; ++i) {
    #pragma unroll
    for (int j = 0; j < 8; ++j) x = __builtin_fmaf(x, 1.0000001f, 1e-9f);
  }
  if (threadIdx.x == 0) o[blockIdx.x & 255] = x;
}

__global__ __launch_bounds__(256) void convert_weights_k(
    const float* __restrict__ W1, const float* __restrict__ W2,
    const float* __restrict__ W3, f16* __restrict__ ws)
{
  int idx = blockIdx.x * 256 + threadIdx.x;
  if (idx < 65536) {
    int kt = idx >> 14, r = idx & 16383, n = r >> 5, kk = r & 31;
    ws[WS_W1 + idx] = (f16)W1[(kt * 32 + kk) * 512 + n];
  } else if (idx < 327680) {
    int i = idx - 65536;
    int kt = i >> 14, r = i & 16383, n = r >> 5, kk = r & 31;
    ws[WS_W2 + i] = (f16)W2[(kt * 32 + kk) * 512 + n];
  } else if (idx < 458752) {
    int i = idx - 327680;
    int kt = i >> 13, r = i & 8191, n = r >> 5, kk = r & 31;
    ws[WS_W3 + i] = (n < 251) ? (f16)W3[(kt * 32 + kk) * 251 + n] : (f16)0.0f;
  }
}

__device__ __forceinline__ f16x8 lds_ld8(const char* base, int m, int strideB, int kb) {
  return *(const f16x8*)(base + m * strideB + (kb ^ ((m & 7) << 4)));
}

__device__ __forceinline__ f16x8 load_x_frag(
    const float* __restrict__ obs, const float* __restrict__ act, long row, int e)
{
  const float* p = (e < 96) ? (obs + row * 96 + e) : (act + row * 32 + (e - 96));
  float4 lo = ((const float4*)p)[0];
  float4 hi = ((const float4*)p)[1];
  f16x8 v;
  v[0] = (f16)lo.x; v[1] = (f16)lo.y; v[2] = (f16)lo.z; v[3] = (f16)lo.w;
  v[4] = (f16)hi.x; v[5] = (f16)hi.y; v[6] = (f16)hi.z; v[7] = (f16)hi.w;
  return v;
}

// --------------------------- GEMM building blocks ---------------------------
template<int KT, int NT>
__device__ __forceinline__ void mlp_stage_reg(
    const char* __restrict__ wlane, int tileB,
    const char* __restrict__ src, int srcStride,
    f32x4 acc[4][NT], int l15, int lh)
{
  #pragma unroll
  for (int kt = 0; kt < KT; ++kt) {
    f16x8 a[NT];
    const char* g = wlane + (size_t)kt * tileB;
    #pragma unroll
    for (int nt = 0; nt < NT; ++nt) a[nt] = *(const f16x8*)(g + nt * 1024);
    __builtin_amdgcn_s_setprio(1);
    #pragma unroll
    for (int mh = 0; mh < 4; ++mh) {
      f16x8 b = lds_ld8(src, mh * 16 + l15, srcStride, kt * 64 + lh * 16);
      #pragma unroll
      for (int nt = 0; nt < NT; ++nt)
        acc[mh][nt] = __builtin_amdgcn_mfma_f32_16x16x32_f16(a[nt], b, acc[mh][nt], 0, 0, 0);
    }
    __builtin_amdgcn_s_setprio(0);
  }
}

__device__ __forceinline__ void mlp_stage1(
    const float* __restrict__ obs, const float* __restrict__ act, long rowBase,
    const char* __restrict__ wlane, f32x4 acc[4][4], int l15, int lh)
{
  #pragma unroll
  for (int kt = 0; kt < 4; ++kt) {
    f16x8 a[4];
    const char* g = wlane + (size_t)kt * 32768;
    #pragma unroll
    for (int nt = 0; nt < 4; ++nt) a[nt] = *(const f16x8*)(g + nt * 1024);
    int e = kt * 32 + lh * 8;
    #pragma unroll
    for (int mh = 0; mh < 4; ++mh) {
      f16x8 b = load_x_frag(obs, act, rowBase + mh * 16 + l15, e);
      #pragma unroll
      for (int nt = 0; nt < 4; ++nt)
        acc[mh][nt] = __builtin_amdgcn_mfma_f32_16x16x32_f16(a[nt], b, acc[mh][nt], 0, 0, 0);
    }
  }
}

template<int NT>
__device__ __forceinline__ void store_act(
    f32x4 acc[4][NT], char* hbuf, const float* __restrict__ bias,
    int w, int l15, int lh)
{
  #pragma unroll
  for (int nt = 0; nt < NT; ++nt) {
    int ncol = w * (NT * 16) + nt * 16 + lh * 4;
    f32x4 bv = *(const f32x4*)(bias + ncol);
    #pragma unroll
    for (int mh = 0; mh < 4; ++mh) {
      int m = mh * 16 + l15;
      f16x4 hv;
      #pragma unroll
      for (int r = 0; r < 4; ++r) {
        float v = acc[mh][nt][r] + bv[r];
        hv[r] = (f16)(v > 0.f ? v : 0.01f * v);
      }
      *(f16x4*)(hbuf + m * 1024 + ((ncol * 2) ^ ((m & 7) << 4))) = hv;
    }
  }
}

// ------------------------------ role bodies ---------------------------------
__device__ __forceinline__ void gemm_body(
    char* smem, int localRowBase, long rowBase,
    const float* __restrict__ obs, const float* __restrict__ act,
    const float* __restrict__ bias1, const float* __restrict__ bias2,
    const float* __restrict__ bias3, const f16* __restrict__ ws,
    float* __restrict__ lgT, int tid)
{
  char* hbuf = smem;
  const int lane = tid & 63;
  const int w = tid >> 6;
  const int l15 = lane & 15;
  const int lh = lane >> 4;
  (void)lane;
  {
    f32x4 acc[4][4];
    #pragma unroll
    for (int mh = 0; mh < 4; ++mh)
      #pragma unroll
      for (int nt = 0; nt < 4; ++nt) acc[mh][nt] = f32x4{0.f, 0.f, 0.f, 0.f};
    const char* wl = (const char*)(ws + WS_W1) + (w * 64 + l15) * 64 + lh * 16;
    mlp_stage1(obs, act, rowBase, wl, acc, l15, lh);
    store_act<4>(acc, hbuf, bias1, w, l15, lh);
  }
  __syncthreads();
  {
    f32x4 acc[4][4];
    #pragma unroll
    for (int mh = 0; mh < 4; ++mh)
      #pragma unroll
      for (int nt = 0; nt < 4; ++nt) acc[mh][nt] = f32x4{0.f, 0.f, 0.f, 0.f};
    const char* wl = (const char*)(ws + WS_W2) + (w * 64 + l15) * 64 + lh * 16;
    mlp_stage_reg<16, 4>(wl, 32768, hbuf, 1024, acc, l15, lh);
    __syncthreads();
    store_act<4>(acc, hbuf, bias2, w, l15, lh);
  }
  __syncthreads();
  {
    f32x4 acc[4][2];
    #pragma unroll
    for (int mh = 0; mh < 4; ++mh)
      #pragma unroll
      for (int nt = 0; nt < 2; ++nt) acc[mh][nt] = f32x4{0.f, 0.f, 0.f, 0.f};
    const char* wl = (const char*)(ws + WS_W3) + (w * 32 + l15) * 64 + lh * 16;
    mlp_stage_reg<16, 2>(wl, 16384, hbuf, 1024, acc, l15, lh);
    #pragma unroll
    for (int nt = 0; nt < 2; ++nt) {
      int abase = w * 32 + nt * 16 + lh * 4;
      float bv[4];
      #pragma unroll
      for (int r = 0; r < 4; ++r) {
        int a = abase + r;
        bv[r] = (a < 251) ? bias3[a] : 0.f;
      }
      #pragma unroll
      for (int mh = 0; mh < 4; ++mh) {
        int m = mh * 16 + l15;
        #pragma unroll
        for (int r = 0; r < 4; ++r) {
          int a = abase + r;
          if (a < 251)
            lgT[(size_t)a * CHUNK_ROWS + localRowBase + m] = acc[mh][nt][r] + bv[r];
        }
      }
    }
  }
}

__device__ __forceinline__ void epi_body(
    float* sh, int localRowBase, long rowBase,
    const float* __restrict__ lgT,
    const float* __restrict__ rewards, const float* __restrict__ bootstrap,
    const float* __restrict__ discount, const float* __restrict__ q_support,
    float* __restrict__ out, int tid)
{
  const int lane = tid & 63;
  const int w = tid >> 6;
  const int a0 = w * 32;

  float e[32];
  #pragma unroll
  for (int i = 0; i < 32; ++i) {
    int a = a0 + i;
    e[i] = (a < 251) ? lgT[(size_t)a * CHUNK_ROWS + localRowBase + lane] : -3.0e38f;
  }
  float m0 = e[0], m1 = e[1], m2 = e[2], m3 = e[3];
  #pragma unroll
  for (int i = 4; i < 32; i += 4) {
    m0 = fmaxf(m0, e[i]);     m1 = fmaxf(m1, e[i + 1]);
    m2 = fmaxf(m2, e[i + 2]); m3 = fmaxf(m3, e[i + 3]);
  }
  sh[w * 64 + lane] = fmaxf(fmaxf(m0, m1), fmaxf(m2, m3));
  float rw = rewards[rowBase + lane];
  float bd = __fmul_rn(bootstrap[rowBase + lane], discount[rowBase + lane]);
  __syncthreads();

  float mx = sh[lane];
  #pragma unroll
  for (int ww = 1; ww < 8; ++ww) mx = fmaxf(mx, sh[ww * 64 + lane]);
  float s0 = 0.f, s1 = 0.f, s2 = 0.f, s3 = 0.f;
  #pragma unroll
  for (int i = 0; i < 32; i += 4) {
    e[i]     = __expf(e[i]     - mx); s0 += e[i];
    e[i + 1] = __expf(e[i + 1] - mx); s1 += e[i + 1];
    e[i + 2] = __expf(e[i + 2] - mx); s2 += e[i + 2];
    e[i + 3] = __expf(e[i + 3] - mx); s3 += e[i + 3];
  }
  sh[512 + w * 64 + lane] = (s0 + s1) + (s2 + s3);
  __syncthreads();

  float tot = sh[512 + lane];
  #pragma unroll
  for (int ww = 1; ww < 8; ++ww) tot += sh[512 + ww * 64 + lane];
  float inv = 1.f / tot;
  __syncthreads();

  #pragma unroll
  for (int z = 0; z < 8; ++z)
    *(f32x4*)((char*)sh + (z * 512 + tid) * 16) = f32x4{0.f, 0.f, 0.f, 0.f};
  __syncthreads();

  #pragma unroll
  for (int i = 0; i < 32; ++i) {
    int a = a0 + i;
    if (a < 251) {
      float p = e[i] * inv;
      float zc = q_support[a];
      float tz = __fadd_rn(rw, __fmul_rn(bd, zc));
      tz = fminf(fmaxf(tz, -100.f), 100.f);
      float b = __fdiv_rn(__fadd_rn(tz, 100.f), 0.8f);
      float lf = floorf(b), uf = ceilf(b);
      int li = (int)lf, ui = (int)uf;
      bool eq = (li == ui);
      int li2 = li - ((eq && (ui > 0)) ? 1 : 0);
      int ui2 = ui + ((eq && (li < 250)) ? 1 : 0);
      atomicAdd(&sh[li2 * 64 + (lane ^ (li2 & 31))], p * ((float)ui2 - b));
      atomicAdd(&sh[ui2 * 64 + (lane ^ (ui2 & 31))], p * (b - (float)li2));
    }
  }
  __syncthreads();

  #pragma unroll 1
  for (int rr = 0; rr < 8; ++rr) {
    int row = w * 8 + rr;
    #pragma unroll
    for (int j = 0; j < 4; ++j) {
      int c = lane + j * 64;
      if (c < 251)
        out[(rowBase + row) * 251 + c] = sh[c * 64 + (row ^ (c & 31))];
    }
  }
}

// ------------------------------- kernels ------------------------------------
__global__ __launch_bounds__(512, 4) void gemm3_k(
    const float* __restrict__ obs, const float* __restrict__ act,
    const float* __restrict__ bias1, const float* __restrict__ bias2,
    const float* __restrict__ bias3, const f16* __restrict__ ws,
    float* __restrict__ lgT, long rowBase0)
{
  extern __shared__ char smem[];
  int lrb = blockIdx.x * 64;
  gemm_body(smem, lrb, rowBase0 + lrb, obs, act, bias1, bias2, bias3, ws, lgT,
            threadIdx.x);
}

__global__ __launch_bounds__(512, 2) void epi_c51_k(
    const float* __restrict__ lgT,
    const float* __restrict__ rewards, const float* __restrict__ bootstrap,
    const float* __restrict__ discount, const float* __restrict__ q_support,
    float* __restrict__ out, long rowBase0)
{
  __shared__ float sh[16384];
  int lrb = blockIdx.x * 64;
  epi_body(sh, lrb, rowBase0 + lrb, lgT, rewards, bootstrap, discount,
           q_support, out, threadIdx.x);
}

// Co-scheduled: even pair-blocks run gemm(chunk cg), odd run epi(chunk ce).
__global__ __launch_bounds__(512, 2) void combined_k(
    const float* __restrict__ obs, const float* __restrict__ act,
    const float* __restrict__ rewards, const float* __restrict__ bootstrap,
    const float* __restrict__ discount, const float* __restrict__ q_support,
    const float* __restrict__ bias1, const float* __restrict__ bias2,
    const float* __restrict__ bias3, const f16* __restrict__ ws,
    float* __restrict__ lgT_g, float* __restrict__ lgT_e,
    float* __restrict__ out, long rbG, long rbE)
{
  extern __shared__ char smem[];
  const int pair = blockIdx.x >> 1;
  const int lrb = pair * 64;
  if ((blockIdx.x & 1) == 0) {
    gemm_body(smem, lrb, rbG + lrb, obs, act, bias1, bias2, bias3, ws, lgT_g,
              threadIdx.x);
  } else {
    epi_body((float*)smem, lrb, rbE + lrb, lgT_e, rewards, bootstrap, discount,
             q_support, out, threadIdx.x);
  }
}

// ---- ABLATION B1: zero + projection chain + LDS atomics (no per-rep store) --
__global__ __launch_bounds__(512, 2) void epi_ablB1_k(
    const float* __restrict__ rewards, const float* __restrict__ bootstrap,
    const float* __restrict__ discount, const float* __restrict__ q_support,
    float* __restrict__ out)
{
  __shared__ float sh[16384];
  const int tid = threadIdx.x, lane = tid & 63, w = tid >> 6;
  const int a0 = w * 32;
  const int localRowBase = blockIdx.x * 64;
  float e[32];
  #pragma unroll
  for (int i = 0; i < 32; ++i)
    e[i] = 1.0f + (float)((lane * 37 + i * 11) & 63) * 0.01f;
  float inv = 0.0041f;
  float rw = rewards[localRowBase + lane];
  float bd = __fmul_rn(bootstrap[localRowBase + lane], discount[localRowBase + lane]);
  #pragma unroll 1
  for (int rep = 0; rep < 8; ++rep) {
    asm volatile("" : "+v"(bd), "+v"(inv));
    #pragma unroll
    for (int z = 0; z < 8; ++z)
      *(f32x4*)((char*)sh + (z * 512 + tid) * 16) = f32x4{0.f, 0.f, 0.f, 0.f};
    __syncthreads();
    #pragma unroll
    for (int i = 0; i < 32; ++i) {
      int a = a0 + i;
      if (a < 251) {
        float p = e[i] * inv;
        float zc = q_support[a];
        float tz = __fadd_rn(rw, __fmul_rn(bd, zc));
        tz = fminf(fmaxf(tz, -100.f), 100.f);
        float b = __fdiv_rn(__fadd_rn(tz, 100.f), 0.8f);
        float lf = floorf(b), uf = ceilf(b);
        int li = (int)lf, ui = (int)uf;
        bool eq = (li == ui);
        int li2 = li - ((eq && (ui > 0)) ? 1 : 0);
        int ui2 = ui + ((eq && (li < 250)) ? 1 : 0);
        atomicAdd(&sh[li2 * 64 + (lane ^ (li2 & 31))], p * ((float)ui2 - b));
        atomicAdd(&sh[ui2 * 64 + (lane ^ (ui2 & 31))], p * (b - (float)li2));
      }
    }
    __syncthreads();
  }
  // single liveness store (chunk0 rows; overwritten by real pipeline)
  out[((size_t)localRowBase + lane) * 251 + w] = sh[tid];
}

// ---- ABLATION B2: LDS read + out store only (x8) ----------------------------
__global__ __launch_bounds__(512, 2) void epi_ablB2_k(float* __restrict__ out)
{
  __shared__ float sh[16384];
  const int tid = threadIdx.x, lane = tid & 63, w = tid >> 6;
  const int localRowBase = blockIdx.x * 64;
  // init once so reads are defined
  #pragma unroll
  for (int z = 0; z < 8; ++z)
    *(f32x4*)((char*)sh + (z * 512 + tid) * 16) = f32x4{0.001f, 0.002f, 0.003f, 0.004f};
  __syncthreads();
  #pragma unroll 1
  for (int rep = 0; rep < 8; ++rep) {
    asm volatile("" ::: "memory");
    #pragma unroll 1
    for (int rr = 0; rr < 8; ++rr) {
      int row = w * 8 + rr;
      #pragma unroll
      for (int j = 0; j < 4; ++j) {
        int c = lane + j * 64;
        if (c < 251)
          out[(size_t)(localRowBase + row) * 251 + c] = sh[c * 64 + (row ^ (c & 31))];
      }
    }
    __syncthreads();
  }
}

// ----------------- fallback: fused kernel (ws too small) --------------------
__global__ __launch_bounds__(512, 4) void fused_c51_k(
    const float* __restrict__ obs, const float* __restrict__ act,
    const float* __restrict__ rewards, const float* __restrict__ bootstrap,
    const float* __restrict__ discount, const float* __restrict__ q_support,
    const float* __restrict__ bias1, const float* __restrict__ bias2,
    const float* __restrict__ bias3, const f16* __restrict__ ws,
    float* __restrict__ out)
{
  extern __shared__ char smem[];
  char* hbuf = smem;
  float* pmax = (float*)(smem + 65536);
  float* psum = (float*)(smem + 65536 + 2048);
  const int tid = threadIdx.x;
  const int lane = tid & 63;
  const int w = tid >> 6;
  const int l15 = lane & 15;
  const int lh = lane >> 4;
  const long rowBase = (long)blockIdx.x * 64;

  {
    f32x4 acc[4][4];
    #pragma unroll
    for (int mh = 0; mh < 4; ++mh)
      #pragma unroll
      for (int nt = 0; nt < 4; ++nt) acc[mh][nt] = f32x4{0.f, 0.f, 0.f, 0.f};
    const char* wl = (const char*)(ws + WS_W1) + (w * 64 + l15) * 64 + lh * 16;
    mlp_stage1(obs, act, rowBase, wl, acc, l15, lh);
    store_act<4>(acc, hbuf, bias1, w, l15, lh);
  }
  __syncthreads();
  {
    f32x4 acc[4][4];
    #pragma unroll
    for (int mh = 0; mh < 4; ++mh)
      #pragma unroll
      for (int nt = 0; nt < 4; ++nt) acc[mh][nt] = f32x4{0.f, 0.f, 0.f, 0.f};
    const char* wl = (const char*)(ws + WS_W2) + (w * 64 + l15) * 64 + lh * 16;
    mlp_stage_reg<16, 4>(wl, 32768, hbuf, 1024, acc, l15, lh);
    __syncthreads();
    store_act<4>(acc, hbuf, bias2, w, l15, lh);
  }
  __syncthreads();
  {
    f32x4 acc[4][2];
    #pragma unroll
    for (int mh = 0; mh < 4; ++mh)
      #pragma unroll
      for (int nt = 0; nt < 2; ++nt) acc[mh][nt] = f32x4{0.f, 0.f, 0.f, 0.f};
    const char* wl = (const char*)(ws + WS_W3) + (w * 32 + l15) * 64 + lh * 16;
    mlp_stage_reg<16, 2>(wl, 16384, hbuf, 1024, acc, l15, lh);
    __syncthreads();
    #pragma unroll
    for (int nt = 0; nt < 2; ++nt) {
      int abase = w * 32 + nt * 16 + lh * 4;
      float bv[4];
      #pragma unroll
      for (int r = 0; r < 4; ++r) {
        int a = abase + r;
        bv[r] = (a < 251) ? bias3[a] : 0.f;
      }
      #pragma unroll
      for (int mh = 0; mh < 4; ++mh) {
        int m = mh * 16 + l15;
        #pragma unroll
        for (int r = 0; r < 4; ++r) {
          int a = abase + r;
          ((float*)hbuf)[a * 64 + m] = (a < 251) ? (acc[mh][nt][r] + bv[r]) : -3.0e38f;
        }
      }
    }
  }
  __syncthreads();
  {
    const float* lgT = (const float*)hbuf;
    float* prT = (float*)hbuf;
    const int a0 = w * 32;
    float e[32];
    #pragma unroll
    for (int i = 0; i < 32; ++i) e[i] = lgT[(a0 + i) * 64 + lane];
    float m0 = e[0], m1 = e[1], m2 = e[2], m3 = e[3];
    #pragma unroll
    for (int i = 4; i < 32; i += 4) {
      m0 = fmaxf(m0, e[i]);     m1 = fmaxf(m1, e[i + 1]);
      m2 = fmaxf(m2, e[i + 2]); m3 = fmaxf(m3, e[i + 3]);
    }
    pmax[w * 64 + lane] = fmaxf(fmaxf(m0, m1), fmaxf(m2, m3));
    float rw = rewards[rowBase + lane];
    float bd = __fmul_rn(bootstrap[rowBase + lane], discount[rowBase + lane]);
    __syncthreads();
    #pragma unroll
    for (int z = 0; z < 8; ++z)
      *(f32x4*)(hbuf + (z * 512 + tid) * 16) = f32x4{0.f, 0.f, 0.f, 0.f};
    float mx = pmax[lane];
    #pragma unroll
    for (int ww = 1; ww < 8; ++ww) mx = fmaxf(mx, pmax[ww * 64 + lane]);
    float s0 = 0.f, s1 = 0.f, s2 = 0.f, s3 = 0.f;
    #pragma unroll
    for (int i = 0; i < 32; i += 4) {
      e[i]     = __expf(e[i]     - mx); s0 += e[i];
      e[i + 1] = __expf(e[i + 1] - mx); s1 += e[i + 1];
      e[i + 2] = __expf(e[i + 2] - mx); s2 += e[i + 2];
      e[i + 3] = __expf(e[i + 3] - mx); s3 += e[i + 3];
    }
    psum[w * 64 + lane] = (s0 + s1) + (s2 + s3);
    __syncthreads();
    float tot = psum[lane];
    #pragma unroll
    for (int ww = 1; ww < 8; ++ww) tot += psum[ww * 64 + lane];
    float inv = 1.f / tot;
    #pragma unroll
    for (int i = 0; i < 32; ++i) {
      int a = a0 + i;
      if (a < 251) {
        float p = e[i] * inv;
        float zc = q_support[a];
        float tz = __fadd_rn(rw, __fmul_rn(bd, zc));
        tz = fminf(fmaxf(tz, -100.f), 100.f);
        float b = __fdiv_rn(__fadd_rn(tz, 100.f), 0.8f);
        float lf = floorf(b), uf = ceilf(b);
        int li = (int)lf, ui = (int)uf;
        bool eq = (li == ui);
        int li2 = li - ((eq && (ui > 0)) ? 1 : 0);
        int ui2 = ui + ((eq && (li < 250)) ? 1 : 0);
        atomicAdd(&prT[li2 * 64 + (lane ^ (li2 & 31))], p * ((float)ui2 - b));
        atomicAdd(&prT[ui2 * 64 + (lane ^ (ui2 & 31))], p * (b - (float)li2));
      }
    }
    __syncthreads();
    for (unsigned i = tid; i < 64u * 251u; i += 512u) {
      unsigned row = i / 251u;
      unsigned c = i - row * 251u;
      out[rowBase * 251 + i] = prT[c * 64 + (row ^ (c & 31))];
    }
  }
}

extern "C" void kernel_launch(void* const* d_in, const int* in_sizes, int n_in,
                              void* d_out, int out_size, void* d_ws, size_t ws_size,
                              hipStream_t stream) {
  (void)n_in; (void)out_size;
  const float* obs       = (const float*)d_in[0];
  const float* actions   = (const float*)d_in[1];
  const float* rewards   = (const float*)d_in[2];
  const float* bootstrap = (const float*)d_in[3];
  const float* discount  = (const float*)d_in[4];
  const float* q_support = (const float*)d_in[5];
  const float* W1 = (const float*)d_in[6];
  const float* b1 = (const float*)d_in[7];
  const float* W2 = (const float*)d_in[8];
  const float* b2 = (const float*)d_in[9];
  const float* W3 = (const float*)d_in[10];
  const float* b3 = (const float*)d_in[11];
  float* out = (float*)d_out;
  f16* ws = (f16*)d_ws;
  const int B = in_sizes[2];

  const size_t need1 = (size_t)LG_OFF + LG_ELEMS * 4;           // 1 lgT buffer
  const size_t need2 = (size_t)LG_OFF + 2 * LG_ELEMS * 4;       // ping-pong
  const int NC = (B % CHUNK_ROWS == 0) ? B / CHUNK_ROWS : 0;

  if (NC >= 2 && ws_size >= need1) {
    float* lgT0 = (float*)((char*)d_ws + LG_OFF);
    float* lgT1 = (ws_size >= need2) ? lgT0 + LG_ELEMS : lgT0;
    float* probe_out = (float*)((char*)d_ws + PROBE_OFF);

    // --- measurement probes (outputs overwritten by real pipeline below) ---
    hipLaunchKernelGGL(loadprobe_k, dim3(2048), dim3(256), 0, stream, probe_out);
    hipLaunchKernelGGL(epi_ablB1_k, dim3(CHUNK_ROWS / 64), dim3(512), 0, stream,
                       rewards, bootstrap, discount, q_support, out);
    hipLaunchKernelGGL(epi_ablB2_k, dim3(CHUNK_ROWS / 64), dim3(512), 0, stream,
                       out);

    // --- real pipeline ---
    hipLaunchKernelGGL(convert_weights_k, dim3(1792), dim3(256), 0, stream,
                       W1, W2, W3, ws);
    const int GEMM_LDS = 65536;
    hipFuncSetAttribute(reinterpret_cast<const void*>(gemm3_k),
                        hipFuncAttributeMaxDynamicSharedMemorySize, GEMM_LDS);
    hipFuncSetAttribute(reinterpret_cast<const void*>(combined_k),
                        hipFuncAttributeMaxDynamicSharedMemorySize, GEMM_LDS);

    if (ws_size >= need2) {
      // software-pipelined: gemm(c+1) co-scheduled with epi(c), ping-pong lgT
      float* lg[2] = {lgT0, lgT1};
      hipLaunchKernelGGL(gemm3_k, dim3(CHUNK_ROWS / 64), dim3(512), GEMM_LDS,
                         stream, obs, actions, b1, b2, b3, ws, lg[0], 0L);
      for (int c = 1; c < NC; ++c) {
        hipLaunchKernelGGL(combined_k, dim3(2 * CHUNK_ROWS / 64), dim3(512),
                           GEMM_LDS, stream,
                           obs, actions, rewards, bootstrap, discount, q_support,
                           b1, b2, b3, ws, lg[c & 1], lg[(c - 1) & 1], out,
                           (long)c * CHUNK_ROWS, (long)(c - 1) * CHUNK_ROWS);
      }
      hipLaunchKernelGGL(epi_c51_k, dim3(CHUNK_ROWS / 64), dim3(512), 0, stream,
                         lg[(NC - 1) & 1], rewards, bootstrap, discount,
                         q_support, out, (long)(NC - 1) * CHUNK_ROWS);
    } else {
      for (int c = 0; c < NC; ++c) {
        long rb = (long)c * CHUNK_ROWS;
        hipLaunchKernelGGL(gemm3_k, dim3(CHUNK_ROWS / 64), dim3(512), GEMM_LDS,
                           stream, obs, actions, b1, b2, b3, ws, lgT0, rb);
        hipLaunchKernelGGL(epi_c51_k, dim3(CHUNK_ROWS / 64), dim3(512), 0, stream,
                           lgT0, rewards, bootstrap, discount, q_support, out, rb);
      }
    }
  } else {
    hipLaunchKernelGGL(convert_weights_k, dim3(1792), dim3(256), 0, stream,
                       W1, W2, W3, ws);
    const int LDS_BYTES = 69632;
    hipFuncSetAttribute(reinterpret_cast<const void*>(fused_c51_k),
                        hipFuncAttributeMaxDynamicSharedMemorySize, LDS_BYTES);
    hipLaunchKernelGGL(fused_c51_k, dim3(B / 64), dim3(512), LDS_BYTES, stream,
                       obs, actions, rewards, bootstrap, discount, q_support,
                       b1, b2, b3, ws, out);
  }
}

// Round 12
// 389.879 us; speedup vs baseline: 4.4296x; 3.7657x over previous
//
#include <hip/hip_runtime.h>
#include <stdint.h>

typedef _Float16 f16;
typedef __attribute__((ext_vector_type(8))) _Float16 f16x8;
typedef __attribute__((ext_vector_type(4))) _Float16 f16x4;
typedef __attribute__((ext_vector_type(4))) float f32x4;

#define WS_W1 0
#define WS_W2 65536
#define WS_W3 327680
#define LG_OFF (1 << 20)
#define CHUNK_ROWS 32768
#define LG_ELEMS ((size_t)251 * CHUNK_ROWS)

__global__ __launch_bounds__(256) void convert_weights_k(
    const float* __restrict__ W1, const float* __restrict__ W2,
    const float* __restrict__ W3, f16* __restrict__ ws)
{
  int idx = blockIdx.x * 256 + threadIdx.x;
  if (idx < 65536) {
    int kt = idx >> 14, r = idx & 16383, n = r >> 5, kk = r & 31;
    ws[WS_W1 + idx] = (f16)W1[(kt * 32 + kk) * 512 + n];
  } else if (idx < 327680) {
    int i = idx - 65536;
    int kt = i >> 14, r = i & 16383, n = r >> 5, kk = r & 31;
    ws[WS_W2 + i] = (f16)W2[(kt * 32 + kk) * 512 + n];
  } else if (idx < 458752) {
    int i = idx - 327680;
    int kt = i >> 13, r = i & 8191, n = r >> 5, kk = r & 31;
    ws[WS_W3 + i] = (n < 251) ? (f16)W3[(kt * 32 + kk) * 251 + n] : (f16)0.0f;
  }
}

__device__ __forceinline__ f16x8 lds_ld8(const char* base, int m, int strideB, int kb) {
  return *(const f16x8*)(base + m * strideB + (kb ^ ((m & 7) << 4)));
}

__device__ __forceinline__ f16x8 load_x_frag(
    const float* __restrict__ obs, const float* __restrict__ act, long row, int e)
{
  const float* p = (e < 96) ? (obs + row * 96 + e) : (act + row * 32 + (e - 96));
  float4 lo = ((const float4*)p)[0];
  float4 hi = ((const float4*)p)[1];
  f16x8 v;
  v[0] = (f16)lo.x; v[1] = (f16)lo.y; v[2] = (f16)lo.z; v[3] = (f16)lo.w;
  v[4] = (f16)hi.x; v[5] = (f16)hi.y; v[6] = (f16)hi.z; v[7] = (f16)hi.w;
  return v;
}

// --------------------------- GEMM building blocks ---------------------------
template<int KT, int NT>
__device__ __forceinline__ void mlp_stage_reg(
    const char* __restrict__ wlane, int tileB,
    const char* __restrict__ src, int srcStride,
    f32x4 acc[4][NT], int l15, int lh)
{
  #pragma unroll
  for (int kt = 0; kt < KT; ++kt) {
    f16x8 a[NT];
    const char* g = wlane + (size_t)kt * tileB;
    #pragma unroll
    for (int nt = 0; nt < NT; ++nt) a[nt] = *(const f16x8*)(g + nt * 1024);
    __builtin_amdgcn_s_setprio(1);
    #pragma unroll
    for (int mh = 0; mh < 4; ++mh) {
      f16x8 b = lds_ld8(src, mh * 16 + l15, srcStride, kt * 64 + lh * 16);
      #pragma unroll
      for (int nt = 0; nt < NT; ++nt)
        acc[mh][nt] = __builtin_amdgcn_mfma_f32_16x16x32_f16(a[nt], b, acc[mh][nt], 0, 0, 0);
    }
    __builtin_amdgcn_s_setprio(0);
  }
}

__device__ __forceinline__ void mlp_stage1(
    const float* __restrict__ obs, const float* __restrict__ act, long rowBase,
    const char* __restrict__ wlane, f32x4 acc[4][4], int l15, int lh)
{
  #pragma unroll
  for (int kt = 0; kt < 4; ++kt) {
    f16x8 a[4];
    const char* g = wlane + (size_t)kt * 32768;
    #pragma unroll
    for (int nt = 0; nt < 4; ++nt) a[nt] = *(const f16x8*)(g + nt * 1024);
    int e = kt * 32 + lh * 8;
    #pragma unroll
    for (int mh = 0; mh < 4; ++mh) {
      f16x8 b = load_x_frag(obs, act, rowBase + mh * 16 + l15, e);
      #pragma unroll
      for (int nt = 0; nt < 4; ++nt)
        acc[mh][nt] = __builtin_amdgcn_mfma_f32_16x16x32_f16(a[nt], b, acc[mh][nt], 0, 0, 0);
    }
  }
}

template<int NT>
__device__ __forceinline__ void store_act(
    f32x4 acc[4][NT], char* hbuf, const float* __restrict__ bias,
    int w, int l15, int lh)
{
  #pragma unroll
  for (int nt = 0; nt < NT; ++nt) {
    int ncol = w * (NT * 16) + nt * 16 + lh * 4;
    f32x4 bv = *(const f32x4*)(bias + ncol);
    #pragma unroll
    for (int mh = 0; mh < 4; ++mh) {
      int m = mh * 16 + l15;
      f16x4 hv;
      #pragma unroll
      for (int r = 0; r < 4; ++r) {
        float v = acc[mh][nt][r] + bv[r];
        hv[r] = (f16)(v > 0.f ? v : 0.01f * v);
      }
      *(f16x4*)(hbuf + m * 1024 + ((ncol * 2) ^ ((m & 7) << 4))) = hv;
    }
  }
}

// ------------------------------ role bodies ---------------------------------
__device__ __forceinline__ void gemm_body(
    char* smem, int localRowBase, long rowBase,
    const float* __restrict__ obs, const float* __restrict__ act,
    const float* __restrict__ bias1, const float* __restrict__ bias2,
    const float* __restrict__ bias3, const f16* __restrict__ ws,
    float* __restrict__ lgT, int tid)
{
  char* hbuf = smem;
  const int lane = tid & 63;
  const int w = tid >> 6;
  const int l15 = lane & 15;
  const int lh = lane >> 4;
  {
    f32x4 acc[4][4];
    #pragma unroll
    for (int mh = 0; mh < 4; ++mh)
      #pragma unroll
      for (int nt = 0; nt < 4; ++nt) acc[mh][nt] = f32x4{0.f, 0.f, 0.f, 0.f};
    const char* wl = (const char*)(ws + WS_W1) + (w * 64 + l15) * 64 + lh * 16;
    mlp_stage1(obs, act, rowBase, wl, acc, l15, lh);
    store_act<4>(acc, hbuf, bias1, w, l15, lh);
  }
  __syncthreads();
  {
    f32x4 acc[4][4];
    #pragma unroll
    for (int mh = 0; mh < 4; ++mh)
      #pragma unroll
      for (int nt = 0; nt < 4; ++nt) acc[mh][nt] = f32x4{0.f, 0.f, 0.f, 0.f};
    const char* wl = (const char*)(ws + WS_W2) + (w * 64 + l15) * 64 + lh * 16;
    mlp_stage_reg<16, 4>(wl, 32768, hbuf, 1024, acc, l15, lh);
    __syncthreads();
    store_act<4>(acc, hbuf, bias2, w, l15, lh);
  }
  __syncthreads();
  {
    f32x4 acc[4][2];
    #pragma unroll
    for (int mh = 0; mh < 4; ++mh)
      #pragma unroll
      for (int nt = 0; nt < 2; ++nt) acc[mh][nt] = f32x4{0.f, 0.f, 0.f, 0.f};
    const char* wl = (const char*)(ws + WS_W3) + (w * 32 + l15) * 64 + lh * 16;
    mlp_stage_reg<16, 2>(wl, 16384, hbuf, 1024, acc, l15, lh);
    #pragma unroll
    for (int nt = 0; nt < 2; ++nt) {
      int abase = w * 32 + nt * 16 + lh * 4;
      float bv[4];
      #pragma unroll
      for (int r = 0; r < 4; ++r) {
        int a = abase + r;
        bv[r] = (a < 251) ? bias3[a] : 0.f;
      }
      #pragma unroll
      for (int mh = 0; mh < 4; ++mh) {
        int m = mh * 16 + l15;
        #pragma unroll
        for (int r = 0; r < 4; ++r) {
          int a = abase + r;
          if (a < 251)
            lgT[(size_t)a * CHUNK_ROWS + localRowBase + m] = acc[mh][nt][r] + bv[r];
        }
      }
    }
  }
}

// Epilogue: lane-per-row softmax + RUN-FLUSH projection scatter.
// b(a) is monotone per lane (bd>=0, step<1) -> floor advances by 0/1; keep two
// register accumulators and flush each finished bin with ONE atomic. Exact-int
// b (eq, clip boundaries) bypasses via direct atomics. fp chain bit-identical.
__device__ __forceinline__ void epi_body(
    float* sh, int localRowBase, long rowBase,
    const float* __restrict__ lgT,
    const float* __restrict__ rewards, const float* __restrict__ bootstrap,
    const float* __restrict__ discount, const float* __restrict__ q_support,
    float* __restrict__ out, int tid)
{
  const int lane = tid & 63;
  const int w = tid >> 6;
  const int a0 = w * 32;

  float e[32];
  #pragma unroll
  for (int i = 0; i < 32; ++i) {
    int a = a0 + i;
    e[i] = (a < 251) ? lgT[(size_t)a * CHUNK_ROWS + localRowBase + lane] : -3.0e38f;
  }
  float m0 = e[0], m1 = e[1], m2 = e[2], m3 = e[3];
  #pragma unroll
  for (int i = 4; i < 32; i += 4) {
    m0 = fmaxf(m0, e[i]);     m1 = fmaxf(m1, e[i + 1]);
    m2 = fmaxf(m2, e[i + 2]); m3 = fmaxf(m3, e[i + 3]);
  }
  sh[w * 64 + lane] = fmaxf(fmaxf(m0, m1), fmaxf(m2, m3));
  float rw = rewards[rowBase + lane];
  float bd = __fmul_rn(bootstrap[rowBase + lane], discount[rowBase + lane]);
  __syncthreads();

  float mx = sh[lane];
  #pragma unroll
  for (int ww = 1; ww < 8; ++ww) mx = fmaxf(mx, sh[ww * 64 + lane]);
  float s0 = 0.f, s1 = 0.f, s2 = 0.f, s3 = 0.f;
  #pragma unroll
  for (int i = 0; i < 32; i += 4) {
    e[i]     = __expf(e[i]     - mx); s0 += e[i];
    e[i + 1] = __expf(e[i + 1] - mx); s1 += e[i + 1];
    e[i + 2] = __expf(e[i + 2] - mx); s2 += e[i + 2];
    e[i + 3] = __expf(e[i + 3] - mx); s3 += e[i + 3];
  }
  sh[512 + w * 64 + lane] = (s0 + s1) + (s2 + s3);
  __syncthreads();

  float tot = sh[512 + lane];
  #pragma unroll
  for (int ww = 1; ww < 8; ++ww) tot += sh[512 + ww * 64 + lane];
  float inv = 1.f / tot;
  __syncthreads();

  #pragma unroll
  for (int z = 0; z < 8; ++z)
    *(f32x4*)((char*)sh + (z * 512 + tid) * 16) = f32x4{0.f, 0.f, 0.f, 0.f};
  __syncthreads();

  // ---- run-flush scatter ----
  int curL = -1;
  float accL = 0.f, accU = 0.f;
  #pragma unroll
  for (int i = 0; i < 32; ++i) {
    int a = a0 + i;
    if (a < 251) {                                   // wave-uniform guard
      float p = e[i] * inv;
      float zc = q_support[a];
      float tz = __fadd_rn(rw, __fmul_rn(bd, zc));
      tz = fminf(fmaxf(tz, -100.f), 100.f);
      float b = __fdiv_rn(__fadd_rn(tz, 100.f), 0.8f);
      float lf = floorf(b), uf = ceilf(b);
      int li = (int)lf, ui = (int)uf;
      bool eq = (li == ui);
      int li2 = li - ((eq && (ui > 0)) ? 1 : 0);
      int ui2 = ui + ((eq && (li < 250)) ? 1 : 0);
      float vl = p * ((float)ui2 - b);
      float vu = p * (b - (float)li2);
      if (eq) {
        atomicAdd(&sh[li2 * 64 + (lane ^ (li2 & 31))], vl);
        atomicAdd(&sh[ui2 * 64 + (lane ^ (ui2 & 31))], vu);
      } else {
        if (li2 != curL) {
          bool step1 = (li2 == curL + 1);
          if (curL >= 0) {
            atomicAdd(&sh[curL * 64 + (lane ^ (curL & 31))], accL);
            if (!step1) {
              int cu = curL + 1;
              atomicAdd(&sh[cu * 64 + (lane ^ (cu & 31))], accU);
            }
          }
          accL = step1 ? accU : 0.f;   // curL<0 -> accU==0, safe either way
          accU = 0.f;
          curL = li2;
        }
        accL += vl;
        accU += vu;
      }
    }
  }
  if (curL >= 0) {
    atomicAdd(&sh[curL * 64 + (lane ^ (curL & 31))], accL);
    int cu = curL + 1;
    atomicAdd(&sh[cu * 64 + (lane ^ (cu & 31))], accU);
  }
  __syncthreads();

  #pragma unroll 1
  for (int rr = 0; rr < 8; ++rr) {
    int row = w * 8 + rr;
    #pragma unroll
    for (int j = 0; j < 4; ++j) {
      int c = lane + j * 64;
      if (c < 251)
        out[(rowBase + row) * 251 + c] = sh[c * 64 + (row ^ (c & 31))];
    }
  }
}

// ------------------------------- kernels ------------------------------------
__global__ __launch_bounds__(512, 4) void gemm3_k(
    const float* __restrict__ obs, const float* __restrict__ act,
    const float* __restrict__ bias1, const float* __restrict__ bias2,
    const float* __restrict__ bias3, const f16* __restrict__ ws,
    float* __restrict__ lgT, long rowBase0)
{
  extern __shared__ char smem[];
  int lrb = blockIdx.x * 64;
  gemm_body(smem, lrb, rowBase0 + lrb, obs, act, bias1, bias2, bias3, ws, lgT,
            threadIdx.x);
}

__global__ __launch_bounds__(512, 2) void epi_c51_k(
    const float* __restrict__ lgT,
    const float* __restrict__ rewards, const float* __restrict__ bootstrap,
    const float* __restrict__ discount, const float* __restrict__ q_support,
    float* __restrict__ out, long rowBase0)
{
  __shared__ float sh[16384];
  int lrb = blockIdx.x * 64;
  epi_body(sh, lrb, rowBase0 + lrb, lgT, rewards, bootstrap, discount,
           q_support, out, threadIdx.x);
}

// Co-scheduled gemm(chunk cg) + epi(chunk ce). Role map exploits round-robin
// dispatch: blocks k and k+256 land on the SAME CU (256%8==0 XCDs, same CU
// slot) -> [0,256)=G, [256,512)=E, [512,768)=G, [768,1024)=E gives each CU a
// G+E resident pair (G,E,G,E in its 4-deep queue).
__global__ __launch_bounds__(512, 2) void combined_k(
    const float* __restrict__ obs, const float* __restrict__ act,
    const float* __restrict__ rewards, const float* __restrict__ bootstrap,
    const float* __restrict__ discount, const float* __restrict__ q_support,
    const float* __restrict__ bias1, const float* __restrict__ bias2,
    const float* __restrict__ bias3, const f16* __restrict__ ws,
    float* __restrict__ lgT_g, float* __restrict__ lgT_e,
    float* __restrict__ out, long rbG, long rbE)
{
  extern __shared__ char smem[];
  const int q = blockIdx.x >> 8;               // 0..3
  const int role = q & 1;                      // 0=gemm, 1=epi
  const int group = ((q >> 1) << 8) | (blockIdx.x & 255);   // 0..511
  const int lrb = group * 64;
  if (role == 0) {
    gemm_body(smem, lrb, rbG + lrb, obs, act, bias1, bias2, bias3, ws, lgT_g,
              threadIdx.x);
  } else {
    epi_body((float*)smem, lrb, rbE + lrb, lgT_e, rewards, bootstrap, discount,
             q_support, out, threadIdx.x);
  }
}

// ----------------- fallback: fused kernel (ws too small) --------------------
__global__ __launch_bounds__(512, 4) void fused_c51_k(
    const float* __restrict__ obs, const float* __restrict__ act,
    const float* __restrict__ rewards, const float* __restrict__ bootstrap,
    const float* __restrict__ discount, const float* __restrict__ q_support,
    const float* __restrict__ bias1, const float* __restrict__ bias2,
    const float* __restrict__ bias3, const f16* __restrict__ ws,
    float* __restrict__ out)
{
  extern __shared__ char smem[];
  char* hbuf = smem;
  float* pmax = (float*)(smem + 65536);
  float* psum = (float*)(smem + 65536 + 2048);
  const int tid = threadIdx.x;
  const int lane = tid & 63;
  const int w = tid >> 6;
  const int l15 = lane & 15;
  const int lh = lane >> 4;
  const long rowBase = (long)blockIdx.x * 64;

  {
    f32x4 acc[4][4];
    #pragma unroll
    for (int mh = 0; mh < 4; ++mh)
      #pragma unroll
      for (int nt = 0; nt < 4; ++nt) acc[mh][nt] = f32x4{0.f, 0.f, 0.f, 0.f};
    const char* wl = (const char*)(ws + WS_W1) + (w * 64 + l15) * 64 + lh * 16;
    mlp_stage1(obs, act, rowBase, wl, acc, l15, lh);
    store_act<4>(acc, hbuf, bias1, w, l15, lh);
  }
  __syncthreads();
  {
    f32x4 acc[4][4];
    #pragma unroll
    for (int mh = 0; mh < 4; ++mh)
      #pragma unroll
      for (int nt = 0; nt < 4; ++nt) acc[mh][nt] = f32x4{0.f, 0.f, 0.f, 0.f};
    const char* wl = (const char*)(ws + WS_W2) + (w * 64 + l15) * 64 + lh * 16;
    mlp_stage_reg<16, 4>(wl, 32768, hbuf, 1024, acc, l15, lh);
    __syncthreads();
    store_act<4>(acc, hbuf, bias2, w, l15, lh);
  }
  __syncthreads();
  {
    f32x4 acc[4][2];
    #pragma unroll
    for (int mh = 0; mh < 4; ++mh)
      #pragma unroll
      for (int nt = 0; nt < 2; ++nt) acc[mh][nt] = f32x4{0.f, 0.f, 0.f, 0.f};
    const char* wl = (const char*)(ws + WS_W3) + (w * 32 + l15) * 64 + lh * 16;
    mlp_stage_reg<16, 2>(wl, 16384, hbuf, 1024, acc, l15, lh);
    __syncthreads();
    #pragma unroll
    for (int nt = 0; nt < 2; ++nt) {
      int abase = w * 32 + nt * 16 + lh * 4;
      float bv[4];
      #pragma unroll
      for (int r = 0; r < 4; ++r) {
        int a = abase + r;
        bv[r] = (a < 251) ? bias3[a] : 0.f;
      }
      #pragma unroll
      for (int mh = 0; mh < 4; ++mh) {
        int m = mh * 16 + l15;
        #pragma unroll
        for (int r = 0; r < 4; ++r) {
          int a = abase + r;
          ((float*)hbuf)[a * 64 + m] = (a < 251) ? (acc[mh][nt][r] + bv[r]) : -3.0e38f;
        }
      }
    }
  }
  __syncthreads();
  {
    const float* lgT = (const float*)hbuf;
    float* prT = (float*)hbuf;
    const int a0 = w * 32;
    float e[32];
    #pragma unroll
    for (int i = 0; i < 32; ++i) e[i] = lgT[(a0 + i) * 64 + lane];
    float m0 = e[0], m1 = e[1], m2 = e[2], m3 = e[3];
    #pragma unroll
    for (int i = 4; i < 32; i += 4) {
      m0 = fmaxf(m0, e[i]);     m1 = fmaxf(m1, e[i + 1]);
      m2 = fmaxf(m2, e[i + 2]); m3 = fmaxf(m3, e[i + 3]);
    }
    pmax[w * 64 + lane] = fmaxf(fmaxf(m0, m1), fmaxf(m2, m3));
    float rw = rewards[rowBase + lane];
    float bd = __fmul_rn(bootstrap[rowBase + lane], discount[rowBase + lane]);
    __syncthreads();
    #pragma unroll
    for (int z = 0; z < 8; ++z)
      *(f32x4*)(hbuf + (z * 512 + tid) * 16) = f32x4{0.f, 0.f, 0.f, 0.f};
    float mx = pmax[lane];
    #pragma unroll
    for (int ww = 1; ww < 8; ++ww) mx = fmaxf(mx, pmax[ww * 64 + lane]);
    float s0 = 0.f, s1 = 0.f, s2 = 0.f, s3 = 0.f;
    #pragma unroll
    for (int i = 0; i < 32; i += 4) {
      e[i]     = __expf(e[i]     - mx); s0 += e[i];
      e[i + 1] = __expf(e[i + 1] - mx); s1 += e[i + 1];
      e[i + 2] = __expf(e[i + 2] - mx); s2 += e[i + 2];
      e[i + 3] = __expf(e[i + 3] - mx); s3 += e[i + 3];
    }
    psum[w * 64 + lane] = (s0 + s1) + (s2 + s3);
    __syncthreads();
    float tot = psum[lane];
    #pragma unroll
    for (int ww = 1; ww < 8; ++ww) tot += psum[ww * 64 + lane];
    float inv = 1.f / tot;
    #pragma unroll
    for (int i = 0; i < 32; ++i) {
      int a = a0 + i;
      if (a < 251) {
        float p = e[i] * inv;
        float zc = q_support[a];
        float tz = __fadd_rn(rw, __fmul_rn(bd, zc));
        tz = fminf(fmaxf(tz, -100.f), 100.f);
        float b = __fdiv_rn(__fadd_rn(tz, 100.f), 0.8f);
        float lf = floorf(b), uf = ceilf(b);
        int li = (int)lf, ui = (int)uf;
        bool eq = (li == ui);
        int li2 = li - ((eq && (ui > 0)) ? 1 : 0);
        int ui2 = ui + ((eq && (li < 250)) ? 1 : 0);
        atomicAdd(&prT[li2 * 64 + (lane ^ (li2 & 31))], p * ((float)ui2 - b));
        atomicAdd(&prT[ui2 * 64 + (lane ^ (ui2 & 31))], p * (b - (float)li2));
      }
    }
    __syncthreads();
    for (unsigned i = tid; i < 64u * 251u; i += 512u) {
      unsigned row = i / 251u;
      unsigned c = i - row * 251u;
      out[rowBase * 251 + i] = prT[c * 64 + (row ^ (c & 31))];
    }
  }
}

extern "C" void kernel_launch(void* const* d_in, const int* in_sizes, int n_in,
                              void* d_out, int out_size, void* d_ws, size_t ws_size,
                              hipStream_t stream) {
  (void)n_in; (void)out_size;
  const float* obs       = (const float*)d_in[0];
  const float* actions   = (const float*)d_in[1];
  const float* rewards   = (const float*)d_in[2];
  const float* bootstrap = (const float*)d_in[3];
  const float* discount  = (const float*)d_in[4];
  const float* q_support = (const float*)d_in[5];
  const float* W1 = (const float*)d_in[6];
  const float* b1 = (const float*)d_in[7];
  const float* W2 = (const float*)d_in[8];
  const float* b2 = (const float*)d_in[9];
  const float* W3 = (const float*)d_in[10];
  const float* b3 = (const float*)d_in[11];
  float* out = (float*)d_out;
  f16* ws = (f16*)d_ws;
  const int B = in_sizes[2];

  const size_t need1 = (size_t)LG_OFF + LG_ELEMS * 4;
  const size_t need2 = (size_t)LG_OFF + 2 * LG_ELEMS * 4;
  const int NC = (B % CHUNK_ROWS == 0) ? B / CHUNK_ROWS : 0;

  hipLaunchKernelGGL(convert_weights_k, dim3(1792), dim3(256), 0, stream,
                     W1, W2, W3, ws);

  if (NC >= 2 && ws_size >= need1) {
    float* lgT0 = (float*)((char*)d_ws + LG_OFF);
    float* lgT1 = (ws_size >= need2) ? lgT0 + LG_ELEMS : lgT0;
    const int GEMM_LDS = 65536;
    hipFuncSetAttribute(reinterpret_cast<const void*>(gemm3_k),
                        hipFuncAttributeMaxDynamicSharedMemorySize, GEMM_LDS);
    hipFuncSetAttribute(reinterpret_cast<const void*>(combined_k),
                        hipFuncAttributeMaxDynamicSharedMemorySize, GEMM_LDS);

    if (ws_size >= need2) {
      float* lg[2] = {lgT0, lgT1};
      hipLaunchKernelGGL(gemm3_k, dim3(CHUNK_ROWS / 64), dim3(512), GEMM_LDS,
                         stream, obs, actions, b1, b2, b3, ws, lg[0], 0L);
      for (int c = 1; c < NC; ++c) {
        hipLaunchKernelGGL(combined_k, dim3(2 * CHUNK_ROWS / 64), dim3(512),
                           GEMM_LDS, stream,
                           obs, actions, rewards, bootstrap, discount, q_support,
                           b1, b2, b3, ws, lg[c & 1], lg[(c - 1) & 1], out,
                           (long)c * CHUNK_ROWS, (long)(c - 1) * CHUNK_ROWS);
      }
      hipLaunchKernelGGL(epi_c51_k, dim3(CHUNK_ROWS / 64), dim3(512), 0, stream,
                         lg[(NC - 1) & 1], rewards, bootstrap, discount,
                         q_support, out, (long)(NC - 1) * CHUNK_ROWS);
    } else {
      for (int c = 0; c < NC; ++c) {
        long rb = (long)c * CHUNK_ROWS;
        hipLaunchKernelGGL(gemm3_k, dim3(CHUNK_ROWS / 64), dim3(512), GEMM_LDS,
                           stream, obs, actions, b1, b2, b3, ws, lgT0, rb);
        hipLaunchKernelGGL(epi_c51_k, dim3(CHUNK_ROWS / 64), dim3(512), 0, stream,
                           lgT0, rewards, bootstrap, discount, q_support, out, rb);
      }
    }
  } else {
    const int LDS_BYTES = 69632;
    hipFuncSetAttribute(reinterpret_cast<const void*>(fused_c51_k),
                        hipFuncAttributeMaxDynamicSharedMemorySize, LDS_BYTES);
    hipLaunchKernelGGL(fused_c51_k, dim3(B / 64), dim3(512), LDS_BYTES, stream,
                       obs, actions, rewards, bootstrap, discount, q_support,
                       b1, b2, b3, ws, out);
  }
}

// Round 13
// 316.937 us; speedup vs baseline: 5.4490x; 1.2301x over previous
//
#include <hip/hip_runtime.h>
#include <stdint.h>

typedef _Float16 f16;
typedef __attribute__((ext_vector_type(8))) _Float16 f16x8;
typedef __attribute__((ext_vector_type(4))) _Float16 f16x4;
typedef __attribute__((ext_vector_type(4))) float f32x4;

// Tiled weight layout in ws (f16 elems), K-tile = 32, tiles n-major [n][32]:
// W1: 4 tiles of [512][32]; W2: 16 tiles of [512][32]; W3: 16 tiles of [256][32]
// (n>=251 zeroed). Wave w's slice of each tile is contiguous (NT*1024B).
#define WS_W1 0
#define WS_W2 65536
#define WS_W3 327680

__global__ __launch_bounds__(256) void convert_weights_k(
    const float* __restrict__ W1, const float* __restrict__ W2,
    const float* __restrict__ W3, f16* __restrict__ ws)
{
  int idx = blockIdx.x * 256 + threadIdx.x;
  if (idx < 65536) {
    int kt = idx >> 14, r = idx & 16383, n = r >> 5, kk = r & 31;
    ws[WS_W1 + idx] = (f16)W1[(kt * 32 + kk) * 512 + n];
  } else if (idx < 327680) {
    int i = idx - 65536;
    int kt = i >> 14, r = i & 16383, n = r >> 5, kk = r & 31;
    ws[WS_W2 + i] = (f16)W2[(kt * 32 + kk) * 512 + n];
  } else if (idx < 458752) {
    int i = idx - 327680;
    int kt = i >> 13, r = i & 8191, n = r >> 5, kk = r & 31;
    ws[WS_W3 + i] = (n < 251) ? (f16)W3[(kt * 32 + kk) * 251 + n] : (f16)0.0f;
  }
}

__device__ __forceinline__ f16x8 lds_ld8(const char* base, int m, int strideB, int kb) {
  return *(const f16x8*)(base + m * strideB + (kb ^ ((m & 7) << 4)));
}

__device__ __forceinline__ f16x8 load_x_frag(
    const float* __restrict__ obs, const float* __restrict__ act, long row, int e)
{
  const float* p = (e < 96) ? (obs + row * 96 + e) : (act + row * 32 + (e - 96));
  float4 lo = ((const float4*)p)[0];
  float4 hi = ((const float4*)p)[1];
  f16x8 v;
  v[0] = (f16)lo.x; v[1] = (f16)lo.y; v[2] = (f16)lo.z; v[3] = (f16)lo.w;
  v[4] = (f16)hi.x; v[5] = (f16)hi.y; v[6] = (f16)hi.z; v[7] = (f16)hi.w;
  return v;
}

// --------------------------- GEMM building blocks ---------------------------
template<int KT, int NT>
__device__ __forceinline__ void mlp_stage_reg(
    const char* __restrict__ wlane, int tileB,
    const char* __restrict__ src, int srcStride,
    f32x4 acc[4][NT], int l15, int lh)
{
  #pragma unroll
  for (int kt = 0; kt < KT; ++kt) {
    f16x8 a[NT];
    const char* g = wlane + (size_t)kt * tileB;
    #pragma unroll
    for (int nt = 0; nt < NT; ++nt) a[nt] = *(const f16x8*)(g + nt * 1024);
    __builtin_amdgcn_s_setprio(1);
    #pragma unroll
    for (int mh = 0; mh < 4; ++mh) {
      f16x8 b = lds_ld8(src, mh * 16 + l15, srcStride, kt * 64 + lh * 16);
      #pragma unroll
      for (int nt = 0; nt < NT; ++nt)
        acc[mh][nt] = __builtin_amdgcn_mfma_f32_16x16x32_f16(a[nt], b, acc[mh][nt], 0, 0, 0);
    }
    __builtin_amdgcn_s_setprio(0);
  }
}

__device__ __forceinline__ void mlp_stage1(
    const float* __restrict__ obs, const float* __restrict__ act, long rowBase,
    const char* __restrict__ wlane, f32x4 acc[4][4], int l15, int lh)
{
  #pragma unroll
  for (int kt = 0; kt < 4; ++kt) {
    f16x8 a[4];
    const char* g = wlane + (size_t)kt * 32768;
    #pragma unroll
    for (int nt = 0; nt < 4; ++nt) a[nt] = *(const f16x8*)(g + nt * 1024);
    int e = kt * 32 + lh * 8;
    #pragma unroll
    for (int mh = 0; mh < 4; ++mh) {
      f16x8 b = load_x_frag(obs, act, rowBase + mh * 16 + l15, e);
      #pragma unroll
      for (int nt = 0; nt < 4; ++nt)
        acc[mh][nt] = __builtin_amdgcn_mfma_f32_16x16x32_f16(a[nt], b, acc[mh][nt], 0, 0, 0);
    }
  }
}

template<int NT>
__device__ __forceinline__ void store_act(
    f32x4 acc[4][NT], char* hbuf, const float* __restrict__ bias,
    int w, int l15, int lh)
{
  #pragma unroll
  for (int nt = 0; nt < NT; ++nt) {
    int ncol = w * (NT * 16) + nt * 16 + lh * 4;
    f32x4 bv = *(const f32x4*)(bias + ncol);
    #pragma unroll
    for (int mh = 0; mh < 4; ++mh) {
      int m = mh * 16 + l15;
      f16x4 hv;
      #pragma unroll
      for (int r = 0; r < 4; ++r) {
        float v = acc[mh][nt][r] + bv[r];
        hv[r] = (f16)(v > 0.f ? v : 0.01f * v);
      }
      *(f16x4*)(hbuf + m * 1024 + ((ncol * 2) ^ ((m & 7) << 4))) = hv;
    }
  }
}

// ------------------------------- fused kernel -------------------------------
// LDS: hbuf 64KB (h1 -> h2 -> lgT[atom][row] -> prT bins overlay)
//      + pmax/psum 4KB strip = 68KB -> 2 blocks/CU.
// (512,2): LDS already caps residency at 2 blocks/CU, so take the full
// 256-VGPR budget (keeps e[32] + W prefetches in registers; R8 lesson).
__global__ __launch_bounds__(512, 2) void fused_c51_k(
    const float* __restrict__ obs, const float* __restrict__ act,
    const float* __restrict__ rewards, const float* __restrict__ bootstrap,
    const float* __restrict__ discount, const float* __restrict__ q_support,
    const float* __restrict__ bias1, const float* __restrict__ bias2,
    const float* __restrict__ bias3, const f16* __restrict__ ws,
    float* __restrict__ out)
{
  extern __shared__ char smem[];
  char* hbuf = smem;                            // 64KB
  float* pmax = (float*)(smem + 65536);         // 2KB
  float* psum = (float*)(smem + 65536 + 2048);  // 2KB

  const int tid = threadIdx.x;
  const int lane = tid & 63;
  const int w = tid >> 6;
  const int l15 = lane & 15;
  const int lh = lane >> 4;
  const long rowBase = (long)blockIdx.x * 64;

  // ---- Stage 1: h1 = leaky(x @ W1 + b1)  (x direct from HBM, W1 from L2)
  {
    f32x4 acc[4][4];
    #pragma unroll
    for (int mh = 0; mh < 4; ++mh)
      #pragma unroll
      for (int nt = 0; nt < 4; ++nt) acc[mh][nt] = f32x4{0.f, 0.f, 0.f, 0.f};
    const char* wl = (const char*)(ws + WS_W1) + (w * 64 + l15) * 64 + lh * 16;
    mlp_stage1(obs, act, rowBase, wl, acc, l15, lh);
    store_act<4>(acc, hbuf, bias1, w, l15, lh);
  }
  __syncthreads();

  // ---- Stage 2: h2 = leaky(h1 @ W2 + b2)
  {
    f32x4 acc[4][4];
    #pragma unroll
    for (int mh = 0; mh < 4; ++mh)
      #pragma unroll
      for (int nt = 0; nt < 4; ++nt) acc[mh][nt] = f32x4{0.f, 0.f, 0.f, 0.f};
    const char* wl = (const char*)(ws + WS_W2) + (w * 64 + l15) * 64 + lh * 16;
    mlp_stage_reg<16, 4>(wl, 32768, hbuf, 1024, acc, l15, lh);
    __syncthreads();   // all waves done reading h1
    store_act<4>(acc, hbuf, bias2, w, l15, lh);
  }
  __syncthreads();

  // ---- Stage 3: lgT[atom][row] = (h2 @ W3 + b3)^T  (LDS, atoms>=251 = -3e38)
  {
    f32x4 acc[4][2];
    #pragma unroll
    for (int mh = 0; mh < 4; ++mh)
      #pragma unroll
      for (int nt = 0; nt < 2; ++nt) acc[mh][nt] = f32x4{0.f, 0.f, 0.f, 0.f};
    const char* wl = (const char*)(ws + WS_W3) + (w * 32 + l15) * 64 + lh * 16;
    mlp_stage_reg<16, 2>(wl, 16384, hbuf, 1024, acc, l15, lh);
    __syncthreads();   // all waves done reading h2
    #pragma unroll
    for (int nt = 0; nt < 2; ++nt) {
      int abase = w * 32 + nt * 16 + lh * 4;
      float bv[4];
      #pragma unroll
      for (int r = 0; r < 4; ++r) {
        int a = abase + r;
        bv[r] = (a < 251) ? bias3[a] : 0.f;
      }
      #pragma unroll
      for (int mh = 0; mh < 4; ++mh) {
        int m = mh * 16 + l15;
        #pragma unroll
        for (int r = 0; r < 4; ++r) {
          int a = abase + r;
          ((float*)hbuf)[a * 64 + m] = (a < 251) ? (acc[mh][nt][r] + bv[r]) : -3.0e38f;
        }
      }
    }
  }
  __syncthreads();

  // ---- Epilogue: lane-per-row softmax + run-flush projection scatter ----
  {
    const float* lgT = (const float*)hbuf;
    float* sh = (float*)hbuf;                 // bins overlay after pass 1
    const int a0 = w * 32;

    // pass 1: wave w's 32 atoms of row `lane` -> registers; partial max
    float e[32];
    #pragma unroll
    for (int i = 0; i < 32; ++i) e[i] = lgT[(a0 + i) * 64 + lane];
    float m0 = e[0], m1 = e[1], m2 = e[2], m3 = e[3];
    #pragma unroll
    for (int i = 4; i < 32; i += 4) {
      m0 = fmaxf(m0, e[i]);     m1 = fmaxf(m1, e[i + 1]);
      m2 = fmaxf(m2, e[i + 2]); m3 = fmaxf(m3, e[i + 3]);
    }
    pmax[w * 64 + lane] = fmaxf(fmaxf(m0, m1), fmaxf(m2, m3));
    float rw = rewards[rowBase + lane];
    float bd = __fmul_rn(bootstrap[rowBase + lane], discount[rowBase + lane]);
    __syncthreads();   // lgT fully consumed into registers; pmax visible

    // zero bins (overlay) + global max + exp + partial sum
    #pragma unroll
    for (int z = 0; z < 8; ++z)
      *(f32x4*)(hbuf + (z * 512 + tid) * 16) = f32x4{0.f, 0.f, 0.f, 0.f};
    float mx = pmax[lane];
    #pragma unroll
    for (int ww = 1; ww < 8; ++ww) mx = fmaxf(mx, pmax[ww * 64 + lane]);
    float s0 = 0.f, s1 = 0.f, s2 = 0.f, s3 = 0.f;
    #pragma unroll
    for (int i = 0; i < 32; i += 4) {
      e[i]     = __expf(e[i]     - mx); s0 += e[i];
      e[i + 1] = __expf(e[i + 1] - mx); s1 += e[i + 1];
      e[i + 2] = __expf(e[i + 2] - mx); s2 += e[i + 2];
      e[i + 3] = __expf(e[i + 3] - mx); s3 += e[i + 3];
    }
    psum[w * 64 + lane] = (s0 + s1) + (s2 + s3);
    __syncthreads();   // zeros + psum visible

    float tot = psum[lane];
    #pragma unroll
    for (int ww = 1; ww < 8; ++ww) tot += psum[ww * 64 + lane];
    float inv = 1.f / tot;

    // run-flush scatter: b(a) is monotone per lane (step bd < 1), so floor
    // advances by 0/1; keep two register accumulators, flush each finished
    // bin with ONE atomic. Exact-int b (eq path) bypasses via direct atomics.
    // Per-atom fp chain bit-identical to reference.
    int curL = -1;
    float accL = 0.f, accU = 0.f;
    #pragma unroll
    for (int i = 0; i < 32; ++i) {
      int a = a0 + i;
      if (a < 251) {                               // wave-uniform guard
        float p = e[i] * inv;
        float zc = q_support[a];
        float tz = __fadd_rn(rw, __fmul_rn(bd, zc));
        tz = fminf(fmaxf(tz, -100.f), 100.f);
        float b = __fdiv_rn(__fadd_rn(tz, 100.f), 0.8f);
        float lf = floorf(b), uf = ceilf(b);
        int li = (int)lf, ui = (int)uf;
        bool eq = (li == ui);
        int li2 = li - ((eq && (ui > 0)) ? 1 : 0);
        int ui2 = ui + ((eq && (li < 250)) ? 1 : 0);
        float vl = p * ((float)ui2 - b);
        float vu = p * (b - (float)li2);
        if (eq) {
          atomicAdd(&sh[li2 * 64 + (lane ^ (li2 & 31))], vl);
          atomicAdd(&sh[ui2 * 64 + (lane ^ (ui2 & 31))], vu);
        } else {
          if (li2 != curL) {
            bool step1 = (li2 == curL + 1);
            if (curL >= 0) {
              atomicAdd(&sh[curL * 64 + (lane ^ (curL & 31))], accL);
              if (!step1) {
                int cu = curL + 1;
                atomicAdd(&sh[cu * 64 + (lane ^ (cu & 31))], accU);
              }
            }
            accL = step1 ? accU : 0.f;
            accU = 0.f;
            curL = li2;
          }
          accL += vl;
          accU += vu;
        }
      }
    }
    if (curL >= 0) {
      atomicAdd(&sh[curL * 64 + (lane ^ (curL & 31))], accL);
      int cu = curL + 1;
      atomicAdd(&sh[cu * 64 + (lane ^ (cu & 31))], accU);
    }
    __syncthreads();

    // out: wave w -> rows w*8..w*8+7 (coalesced, no division)
    #pragma unroll 1
    for (int rr = 0; rr < 8; ++rr) {
      int row = w * 8 + rr;
      #pragma unroll
      for (int j = 0; j < 4; ++j) {
        int c = lane + j * 64;
        if (c < 251)
          out[(rowBase + row) * 251 + c] = sh[c * 64 + (row ^ (c & 31))];
      }
    }
  }
}

extern "C" void kernel_launch(void* const* d_in, const int* in_sizes, int n_in,
                              void* d_out, int out_size, void* d_ws, size_t ws_size,
                              hipStream_t stream) {
  (void)n_in; (void)out_size; (void)ws_size;
  const float* obs       = (const float*)d_in[0];
  const float* actions   = (const float*)d_in[1];
  const float* rewards   = (const float*)d_in[2];
  const float* bootstrap = (const float*)d_in[3];
  const float* discount  = (const float*)d_in[4];
  const float* q_support = (const float*)d_in[5];
  const float* W1 = (const float*)d_in[6];
  const float* b1 = (const float*)d_in[7];
  const float* W2 = (const float*)d_in[8];
  const float* b2 = (const float*)d_in[9];
  const float* W3 = (const float*)d_in[10];
  const float* b3 = (const float*)d_in[11];
  float* out = (float*)d_out;
  f16* ws = (f16*)d_ws;
  const int B = in_sizes[2];

  hipLaunchKernelGGL(convert_weights_k, dim3(1792), dim3(256), 0, stream,
                     W1, W2, W3, ws);

  const int LDS_BYTES = 69632;  // 68 KB -> 2 blocks/CU
  hipFuncSetAttribute(reinterpret_cast<const void*>(fused_c51_k),
                      hipFuncAttributeMaxDynamicSharedMemorySize, LDS_BYTES);
  hipLaunchKernelGGL(fused_c51_k, dim3(B / 64), dim3(512), LDS_BYTES, stream,
                     obs, actions, rewards, bootstrap, discount, q_support,
                     b1, b2, b3, ws, out);
}

// Round 14
// 314.564 us; speedup vs baseline: 5.4901x; 1.0075x over previous
//
#include <hip/hip_runtime.h>
#include <stdint.h>

typedef _Float16 f16;
typedef __attribute__((ext_vector_type(8))) _Float16 f16x8;
typedef __attribute__((ext_vector_type(4))) _Float16 f16x4;
typedef __attribute__((ext_vector_type(4))) float f32x4;

// Tiled weight layout in ws (f16 elems), K-tile = 32, tiles n-major [n][32]:
// W1: 4 tiles of [512][32]; W2: 16 tiles of [512][32]; W3: 16 tiles of [256][32]
// (n>=251 zeroed). Wave w's slice of each tile is contiguous (NT*1024B).
#define WS_W1 0
#define WS_W2 65536
#define WS_W3 327680

__global__ __launch_bounds__(256) void convert_weights_k(
    const float* __restrict__ W1, const float* __restrict__ W2,
    const float* __restrict__ W3, f16* __restrict__ ws)
{
  int idx = blockIdx.x * 256 + threadIdx.x;
  if (idx < 65536) {
    int kt = idx >> 14, r = idx & 16383, n = r >> 5, kk = r & 31;
    ws[WS_W1 + idx] = (f16)W1[(kt * 32 + kk) * 512 + n];
  } else if (idx < 327680) {
    int i = idx - 65536;
    int kt = i >> 14, r = i & 16383, n = r >> 5, kk = r & 31;
    ws[WS_W2 + i] = (f16)W2[(kt * 32 + kk) * 512 + n];
  } else if (idx < 458752) {
    int i = idx - 327680;
    int kt = i >> 13, r = i & 8191, n = r >> 5, kk = r & 31;
    ws[WS_W3 + i] = (n < 251) ? (f16)W3[(kt * 32 + kk) * 251 + n] : (f16)0.0f;
  }
}

__device__ __forceinline__ f16x8 lds_ld8(const char* base, int m, int strideB, int kb) {
  return *(const f16x8*)(base + m * strideB + (kb ^ ((m & 7) << 4)));
}

__device__ __forceinline__ f16x8 load_x_frag(
    const float* __restrict__ obs, const float* __restrict__ act, long row, int e)
{
  const float* p = (e < 96) ? (obs + row * 96 + e) : (act + row * 32 + (e - 96));
  float4 lo = ((const float4*)p)[0];
  float4 hi = ((const float4*)p)[1];
  f16x8 v;
  v[0] = (f16)lo.x; v[1] = (f16)lo.y; v[2] = (f16)lo.z; v[3] = (f16)lo.w;
  v[4] = (f16)hi.x; v[5] = (f16)hi.y; v[6] = (f16)hi.z; v[7] = (f16)hi.w;
  return v;
}

// --------------------------- GEMM building blocks ---------------------------
template<int KT, int NT>
__device__ __forceinline__ void mlp_stage_reg(
    const char* __restrict__ wlane, int tileB,
    const char* __restrict__ src, int srcStride,
    f32x4 acc[4][NT], int l15, int lh)
{
  #pragma unroll
  for (int kt = 0; kt < KT; ++kt) {
    f16x8 a[NT];
    const char* g = wlane + (size_t)kt * tileB;
    #pragma unroll
    for (int nt = 0; nt < NT; ++nt) a[nt] = *(const f16x8*)(g + nt * 1024);
    __builtin_amdgcn_s_setprio(1);
    #pragma unroll
    for (int mh = 0; mh < 4; ++mh) {
      f16x8 b = lds_ld8(src, mh * 16 + l15, srcStride, kt * 64 + lh * 16);
      #pragma unroll
      for (int nt = 0; nt < NT; ++nt)
        acc[mh][nt] = __builtin_amdgcn_mfma_f32_16x16x32_f16(a[nt], b, acc[mh][nt], 0, 0, 0);
    }
    __builtin_amdgcn_s_setprio(0);
  }
}

__device__ __forceinline__ void mlp_stage1(
    const float* __restrict__ obs, const float* __restrict__ act, long rowBase,
    const char* __restrict__ wlane, f32x4 acc[4][4], int l15, int lh)
{
  #pragma unroll
  for (int kt = 0; kt < 4; ++kt) {
    f16x8 a[4];
    const char* g = wlane + (size_t)kt * 32768;
    #pragma unroll
    for (int nt = 0; nt < 4; ++nt) a[nt] = *(const f16x8*)(g + nt * 1024);
    int e = kt * 32 + lh * 8;
    #pragma unroll
    for (int mh = 0; mh < 4; ++mh) {
      f16x8 b = load_x_frag(obs, act, rowBase + mh * 16 + l15, e);
      #pragma unroll
      for (int nt = 0; nt < 4; ++nt)
        acc[mh][nt] = __builtin_amdgcn_mfma_f32_16x16x32_f16(a[nt], b, acc[mh][nt], 0, 0, 0);
    }
  }
}

template<int NT>
__device__ __forceinline__ void store_act(
    f32x4 acc[4][NT], char* hbuf, const float* __restrict__ bias,
    int w, int l15, int lh)
{
  #pragma unroll
  for (int nt = 0; nt < NT; ++nt) {
    int ncol = w * (NT * 16) + nt * 16 + lh * 4;
    f32x4 bv = *(const f32x4*)(bias + ncol);
    #pragma unroll
    for (int mh = 0; mh < 4; ++mh) {
      int m = mh * 16 + l15;
      f16x4 hv;
      #pragma unroll
      for (int r = 0; r < 4; ++r) {
        float v = acc[mh][nt][r] + bv[r];
        hv[r] = (f16)(v > 0.f ? v : 0.01f * v);
      }
      *(f16x4*)(hbuf + m * 1024 + ((ncol * 2) ^ ((m & 7) << 4))) = hv;
    }
  }
}

// ------------------------------- fused kernel -------------------------------
// LDS: hbuf 64KB (h1 -> h2 -> lg[row][atom] -> bins[bin][row] overlay)
//      + pmax/psum 4KB strip = 68KB.
// (512,2): LDS-limited residency; full register budget (R8/R13 lesson).
// Logits layout lg[row][atom] f32 with byte XOR ((row&31)<<4):
//   - stage-3 writes f32x4 (8 per thread, was 32 scalar)
//   - epi pass-1 reads b128 (8 per thread, was 32 scalar)
//   - conflict-free: chunk = cj ^ (lane&31) spreads 8 bank groups, 2 lanes/bank.
__global__ __launch_bounds__(512, 2) void fused_c51_k(
    const float* __restrict__ obs, const float* __restrict__ act,
    const float* __restrict__ rewards, const float* __restrict__ bootstrap,
    const float* __restrict__ discount, const float* __restrict__ q_support,
    const float* __restrict__ bias1, const float* __restrict__ bias2,
    const float* __restrict__ bias3, const f16* __restrict__ ws,
    float* __restrict__ out)
{
  extern __shared__ char smem[];
  char* hbuf = smem;                            // 64KB
  float* pmax = (float*)(smem + 65536);         // 2KB
  float* psum = (float*)(smem + 65536 + 2048);  // 2KB

  const int tid = threadIdx.x;
  const int lane = tid & 63;
  const int w = tid >> 6;
  const int l15 = lane & 15;
  const int lh = lane >> 4;
  const long rowBase = (long)blockIdx.x * 64;

  // ---- Stage 1: h1 = leaky(x @ W1 + b1)  (x direct from HBM, W1 from L2)
  {
    f32x4 acc[4][4];
    #pragma unroll
    for (int mh = 0; mh < 4; ++mh)
      #pragma unroll
      for (int nt = 0; nt < 4; ++nt) acc[mh][nt] = f32x4{0.f, 0.f, 0.f, 0.f};
    const char* wl = (const char*)(ws + WS_W1) + (w * 64 + l15) * 64 + lh * 16;
    mlp_stage1(obs, act, rowBase, wl, acc, l15, lh);
    store_act<4>(acc, hbuf, bias1, w, l15, lh);
  }
  __syncthreads();

  // ---- Stage 2: h2 = leaky(h1 @ W2 + b2)
  {
    f32x4 acc[4][4];
    #pragma unroll
    for (int mh = 0; mh < 4; ++mh)
      #pragma unroll
      for (int nt = 0; nt < 4; ++nt) acc[mh][nt] = f32x4{0.f, 0.f, 0.f, 0.f};
    const char* wl = (const char*)(ws + WS_W2) + (w * 64 + l15) * 64 + lh * 16;
    mlp_stage_reg<16, 4>(wl, 32768, hbuf, 1024, acc, l15, lh);
    __syncthreads();   // all waves done reading h1
    store_act<4>(acc, hbuf, bias2, w, l15, lh);
  }
  __syncthreads();

  // ---- Stage 3: lg[row][atom] = h2 @ W3 + b3  (vectorized swizzled store)
  {
    f32x4 acc[4][2];
    #pragma unroll
    for (int mh = 0; mh < 4; ++mh)
      #pragma unroll
      for (int nt = 0; nt < 2; ++nt) acc[mh][nt] = f32x4{0.f, 0.f, 0.f, 0.f};
    const char* wl = (const char*)(ws + WS_W3) + (w * 32 + l15) * 64 + lh * 16;
    mlp_stage_reg<16, 2>(wl, 16384, hbuf, 1024, acc, l15, lh);
    __syncthreads();   // all waves done reading h2
    #pragma unroll
    for (int nt = 0; nt < 2; ++nt) {
      int abase = w * 32 + nt * 16 + lh * 4;
      float bv[4];
      #pragma unroll
      for (int r = 0; r < 4; ++r) {
        int a = abase + r;
        bv[r] = (a < 251) ? bias3[a] : 0.f;
      }
      #pragma unroll
      for (int mh = 0; mh < 4; ++mh) {
        int m = mh * 16 + l15;
        f32x4 val;
        #pragma unroll
        for (int r = 0; r < 4; ++r) {
          int a = abase + r;
          val[r] = (a < 251) ? (acc[mh][nt][r] + bv[r]) : -3.0e38f;
        }
        *(f32x4*)(hbuf + m * 1024 + ((abase * 4) ^ ((m & 31) << 4))) = val;
      }
    }
  }
  __syncthreads();

  // ---- Epilogue: lane-per-row softmax + run-flush projection scatter ----
  {
    float* sh = (float*)hbuf;                 // bins overlay after pass 1
    const int a0 = w * 32;

    // pass 1: wave w's 32 atoms of row `lane` -> registers (8x b128); max
    float e[32];
    #pragma unroll
    for (int j = 0; j < 8; ++j) {
      f32x4 v = *(const f32x4*)(hbuf + lane * 1024 +
                                (((a0 + j * 4) * 4) ^ ((lane & 31) << 4)));
      e[j * 4 + 0] = v[0]; e[j * 4 + 1] = v[1];
      e[j * 4 + 2] = v[2]; e[j * 4 + 3] = v[3];
    }
    float m0 = e[0], m1 = e[1], m2 = e[2], m3 = e[3];
    #pragma unroll
    for (int i = 4; i < 32; i += 4) {
      m0 = fmaxf(m0, e[i]);     m1 = fmaxf(m1, e[i + 1]);
      m2 = fmaxf(m2, e[i + 2]); m3 = fmaxf(m3, e[i + 3]);
    }
    pmax[w * 64 + lane] = fmaxf(fmaxf(m0, m1), fmaxf(m2, m3));
    float rw = rewards[rowBase + lane];
    float bd = __fmul_rn(bootstrap[rowBase + lane], discount[rowBase + lane]);
    __syncthreads();   // lg fully consumed into registers; pmax visible

    // zero bins (overlay) + global max + exp + partial sum
    #pragma unroll
    for (int z = 0; z < 8; ++z)
      *(f32x4*)(hbuf + (z * 512 + tid) * 16) = f32x4{0.f, 0.f, 0.f, 0.f};
    float mx = pmax[lane];
    #pragma unroll
    for (int ww = 1; ww < 8; ++ww) mx = fmaxf(mx, pmax[ww * 64 + lane]);
    float s0 = 0.f, s1 = 0.f, s2 = 0.f, s3 = 0.f;
    #pragma unroll
    for (int i = 0; i < 32; i += 4) {
      e[i]     = __expf(e[i]     - mx); s0 += e[i];
      e[i + 1] = __expf(e[i + 1] - mx); s1 += e[i + 1];
      e[i + 2] = __expf(e[i + 2] - mx); s2 += e[i + 2];
      e[i + 3] = __expf(e[i + 3] - mx); s3 += e[i + 3];
    }
    psum[w * 64 + lane] = (s0 + s1) + (s2 + s3);
    __syncthreads();   // zeros + psum visible

    float tot = psum[lane];
    #pragma unroll
    for (int ww = 1; ww < 8; ++ww) tot += psum[ww * 64 + lane];
    float inv = 1.f / tot;

    // run-flush scatter: b(a) monotone per lane (step bd < 1) -> floor
    // advances by 0/1; two register accumulators, one atomic per finished
    // bin. Exact-int b (eq path) bypasses via direct atomics. Per-atom fp
    // chain bit-identical to reference.
    int curL = -1;
    float accL = 0.f, accU = 0.f;
    #pragma unroll
    for (int i = 0; i < 32; ++i) {
      int a = a0 + i;
      if (a < 251) {                               // wave-uniform guard
        float p = e[i] * inv;
        float zc = q_support[a];
        float tz = __fadd_rn(rw, __fmul_rn(bd, zc));
        tz = fminf(fmaxf(tz, -100.f), 100.f);
        float b = __fdiv_rn(__fadd_rn(tz, 100.f), 0.8f);
        float lf = floorf(b), uf = ceilf(b);
        int li = (int)lf, ui = (int)uf;
        bool eq = (li == ui);
        int li2 = li - ((eq && (ui > 0)) ? 1 : 0);
        int ui2 = ui + ((eq && (li < 250)) ? 1 : 0);
        float vl = p * ((float)ui2 - b);
        float vu = p * (b - (float)li2);
        if (eq) {
          atomicAdd(&sh[li2 * 64 + (lane ^ (li2 & 31))], vl);
          atomicAdd(&sh[ui2 * 64 + (lane ^ (ui2 & 31))], vu);
        } else {
          if (li2 != curL) {
            bool step1 = (li2 == curL + 1);
            if (curL >= 0) {
              atomicAdd(&sh[curL * 64 + (lane ^ (curL & 31))], accL);
              if (!step1) {
                int cu = curL + 1;
                atomicAdd(&sh[cu * 64 + (lane ^ (cu & 31))], accU);
              }
            }
            accL = step1 ? accU : 0.f;
            accU = 0.f;
            curL = li2;
          }
          accL += vl;
          accU += vu;
        }
      }
    }
    if (curL >= 0) {
      atomicAdd(&sh[curL * 64 + (lane ^ (curL & 31))], accL);
      int cu = curL + 1;
      atomicAdd(&sh[cu * 64 + (lane ^ (cu & 31))], accU);
    }
    __syncthreads();

    // out: wave w -> rows w*8..w*8+7 (coalesced, no division)
    #pragma unroll 1
    for (int rr = 0; rr < 8; ++rr) {
      int row = w * 8 + rr;
      #pragma unroll
      for (int j = 0; j < 4; ++j) {
        int c = lane + j * 64;
        if (c < 251)
          out[(rowBase + row) * 251 + c] = sh[c * 64 + (row ^ (c & 31))];
      }
    }
  }
}

extern "C" void kernel_launch(void* const* d_in, const int* in_sizes, int n_in,
                              void* d_out, int out_size, void* d_ws, size_t ws_size,
                              hipStream_t stream) {
  (void)n_in; (void)out_size; (void)ws_size;
  const float* obs       = (const float*)d_in[0];
  const float* actions   = (const float*)d_in[1];
  const float* rewards   = (const float*)d_in[2];
  const float* bootstrap = (const float*)d_in[3];
  const float* discount  = (const float*)d_in[4];
  const float* q_support = (const float*)d_in[5];
  const float* W1 = (const float*)d_in[6];
  const float* b1 = (const float*)d_in[7];
  const float* W2 = (const float*)d_in[8];
  const float* b2 = (const float*)d_in[9];
  const float* W3 = (const float*)d_in[10];
  const float* b3 = (const float*)d_in[11];
  float* out = (float*)d_out;
  f16* ws = (f16*)d_ws;
  const int B = in_sizes[2];

  hipLaunchKernelGGL(convert_weights_k, dim3(1792), dim3(256), 0, stream,
                     W1, W2, W3, ws);

  const int LDS_BYTES = 69632;  // 68 KB
  hipFuncSetAttribute(reinterpret_cast<const void*>(fused_c51_k),
                      hipFuncAttributeMaxDynamicSharedMemorySize, LDS_BYTES);
  hipLaunchKernelGGL(fused_c51_k, dim3(B / 64), dim3(512), LDS_BYTES, stream,
                     obs, actions, rewards, bootstrap, discount, q_support,
                     b1, b2, b3, ws, out);
}